// Round 12
// baseline (197.754 us; speedup 1.0000x reference)
//
#include <hip/hip_runtime.h>
#include <hip/hip_bf16.h>
#include <math.h>

#define BB 4
#define SS 2048
#define DD 512
#define HH 8
#define DHH 64
#define MROWS (BB*SS)

constexpr float SCALE  = 0.044194173824159216f;            // 1/sqrt(512)
constexpr float QSCALE = (float)(0.044194173824159216 * 1.4426950408889634); // SCALE*log2(e)
constexpr float LN_EPS = 1e-5f;

typedef __attribute__((ext_vector_type(8)))  short bf16x8;
typedef __attribute__((ext_vector_type(4)))  float f32x4;
typedef __attribute__((ext_vector_type(16))) float f32x16;

__device__ __forceinline__ ushort f2bf(float f) {
    __hip_bfloat16 h = __float2bfloat16(f);
    ushort u; __builtin_memcpy(&u, &h, 2);
    return u;
}

__device__ __forceinline__ float exp2_hw(float x) {
#if __has_builtin(__builtin_amdgcn_exp2f)
    return __builtin_amdgcn_exp2f(x);
#else
    return exp2f(x);
#endif
}

__device__ __forceinline__ unsigned cvt_pk_bf16(float lo, float hi) {
    unsigned r;
    asm("v_cvt_pk_bf16_f32 %0, %1, %2" : "=v"(r) : "v"(lo), "v"(hi));
    return r;
}
__device__ __forceinline__ void plane_swap(unsigned &a, unsigned &b) {
    asm("v_permlane32_swap_b32 %0, %1" : "+v"(a), "+v"(b));
}
__device__ __forceinline__ void plane_swapf(float &a, float &b) {
    asm("v_permlane32_swap_b32 %0, %1" : "+v"(a), "+v"(b));
}
__device__ __forceinline__ bf16x8 pack4(unsigned a0, unsigned a1, unsigned b0, unsigned b1) {
    union { unsigned u[4]; bf16x8 v; } x;
    x.u[0] = a0; x.u[1] = a1; x.u[2] = b0; x.u[3] = b1;
    return x.v;
}

__device__ __forceinline__ void gload16(const void* gsrc, void* lds_dst) {
    __builtin_amdgcn_global_load_lds(
        (const __attribute__((address_space(1))) unsigned int*)gsrc,
        (__attribute__((address_space(3))) unsigned int*)lds_dst,
        16, 0, 0);
}

// ---------------------------------------------------------------------------
// Weight cast/pack only: wb = bf16([wq*QS; wk; wv; wo]); biasc = [bq*QS,bk,bv]
// grid 512, block 256
// ---------------------------------------------------------------------------
__global__ __launch_bounds__(256) void wcast_kernel(
    const float* __restrict__ wq, const float* __restrict__ wk,
    const float* __restrict__ wv, const float* __restrict__ wo,
    const float* __restrict__ bq, const float* __restrict__ bk,
    const float* __restrict__ bv,
    ushort* __restrict__ wb, float* __restrict__ biasc)
{
    const int gid = blockIdx.x * 256 + threadIdx.x;
    if (gid < 1536) {
        float v = gid < 512 ? bq[gid] * QSCALE
                : gid < 1024 ? bk[gid - 512] : bv[gid - 1024];
        biasc[gid] = v;
    }
    const int NW4 = (DD * DD) / 4;        // 65536
    for (int j = gid; j < 4 * NW4; j += gridDim.x * 256) {
        int which = j >> 16;
        int off = j & 65535;
        const float4* src = which == 0 ? (const float4*)wq
                          : which == 1 ? (const float4*)wk
                          : which == 2 ? (const float4*)wv : (const float4*)wo;
        float4 v = src[off];
        float scl = which == 0 ? QSCALE : 1.0f;
        ushort4 o = { f2bf(v.x * scl), f2bf(v.y * scl),
                      f2bf(v.z * scl), f2bf(v.w * scl) };
        ((ushort4*)wb)[j] = o;
    }
}

// ---------------------------------------------------------------------------
// Shared GEMM-BT machinery (validated rounds 2-11)
// ---------------------------------------------------------------------------
__device__ __forceinline__ void stage_tile(const ushort* __restrict__ g, int k0,
                                           ushort* lbuf, int t)
{
    #pragma unroll
    for (int i = 0; i < 4; ++i) {
        int cc = i * 256 + t;
        int row = cc >> 3, slot = cc & 7;
        gload16(g + row * DD + k0 + ((slot ^ (row & 7)) << 3), lbuf + cc * 8);
    }
}

// f32 source variant with inline bf16 convert (swizzle applied on ds_write
// side -- per-lane LDS writes, rule #21 satisfied)
__device__ __forceinline__ void stage_xtile(const float* __restrict__ g, int k0,
                                            ushort* lbuf, int t)
{
    #pragma unroll
    for (int i = 0; i < 4; ++i) {
        int cc = i * 256 + t;
        int row = cc >> 3, slot = cc & 7;
        const float* src = g + (size_t)row * DD + k0 + ((slot ^ (row & 7)) << 3);
        float4 a = *(const float4*)src;
        float4 b = *(const float4*)(src + 4);
        uint4 v = { cvt_pk_bf16(a.x, a.y), cvt_pk_bf16(a.z, a.w),
                    cvt_pk_bf16(b.x, b.y), cvt_pk_bf16(b.z, b.w) };
        *(uint4*)(lbuf + cc * 8) = v;
    }
}

__device__ __forceinline__ void mma_step(const ushort* Abuf, const ushort* Bbuf,
                                         int wr, int wc, int c, int g,
                                         f32x4 (&acc)[4][4])
{
    bf16x8 af[2][4], bf[2][4];
    #pragma unroll
    for (int kc = 0; kc < 2; ++kc) {
        int sw = ((kc * 4 + g) ^ (c & 7)) << 4;
        #pragma unroll
        for (int mi = 0; mi < 4; ++mi)
            af[kc][mi] = *(const bf16x8*)((const char*)Abuf + (wr*64 + mi*16 + c)*128 + sw);
        #pragma unroll
        for (int ni = 0; ni < 4; ++ni)
            bf[kc][ni] = *(const bf16x8*)((const char*)Bbuf + (wc*64 + ni*16 + c)*128 + sw);
    }
    __builtin_amdgcn_s_setprio(1);
    #pragma unroll
    for (int kc = 0; kc < 2; ++kc)
        #pragma unroll
        for (int mi = 0; mi < 4; ++mi)
            #pragma unroll
            for (int ni = 0; ni < 4; ++ni)
                acc[mi][ni] = __builtin_amdgcn_mfma_f32_16x16x32_bf16(
                    af[kc][mi], bf[kc][ni], acc[mi][ni], 0, 0, 0);
    __builtin_amdgcn_s_setprio(0);
}

// ---------------------------------------------------------------------------
// QKV projection GEMM. grid (12, 64). A staged from f32 x with inline cvt
// (cast pass eliminated). Coalesced fragment-major epilogue (round-11).
//  Q: [bh][q/32][d/8][q%32][8]   K: [bh][s/64][d/8][s%64][8]
//  V: [bh][s/64][(s%64)/8][d][8] (transposed)
// ---------------------------------------------------------------------------
__global__ __launch_bounds__(256) void qkv_mm(
    const float* __restrict__ x, const ushort* __restrict__ wb,
    const float* __restrict__ biasc,
    ushort* __restrict__ Qb, ushort* __restrict__ Kb, ushort* __restrict__ Vtb)
{
    __shared__ char smem[34816];            // Abuf16K + Bbuf16K; epi 4x8704
    ushort* Abuf = (ushort*)smem;
    ushort* Bbuf = (ushort*)(smem + 16384);

    const int t = threadIdx.x, w = t >> 6, lane = t & 63;
    const int wr = w >> 1, wc = w & 1, c = lane & 15, g = lane >> 4;
    const int nblk = blockIdx.x, mblk = blockIdx.y;

    const float*  Ag = x  + (size_t)mblk * 128 * DD;
    const ushort* Bg = wb + (size_t)nblk * 128 * DD;

    f32x4 acc[4][4] = {};

    for (int k0 = 0; k0 < DD; k0 += 64) {
        stage_xtile(Ag, k0, Abuf, t);
        stage_tile(Bg, k0, Bbuf, t);
        __syncthreads();
        mma_step(Abuf, Bbuf, wr, wc, c, g, acc);
        __syncthreads();                    // frees Abuf/Bbuf for epilogue
    }

    // ---- wave-private LDS retile (stride 68 ushorts) ----
    ushort* E = (ushort*)(smem + (size_t)w * 8704);
    const int n0w  = nblk*128 + wc*64;
    const int proj = n0w >> 9;
    const int h    = (n0w & 511) >> 6;
    const int m0w  = mblk*128 + wr*64;
    const int bi   = m0w >> 11;
    const int st0  = m0w & 2047;

    if (proj == 2) {
        #pragma unroll
        for (int mi = 0; mi < 4; ++mi)
            #pragma unroll
            for (int ni = 0; ni < 4; ++ni) {
                float bias = biasc[n0w + ni*16 + c];
                ushort4 pk = { f2bf(acc[mi][ni][0]+bias), f2bf(acc[mi][ni][1]+bias),
                               f2bf(acc[mi][ni][2]+bias), f2bf(acc[mi][ni][3]+bias) };
                *(ushort4*)&E[(ni*16 + c)*68 + mi*16 + g*4] = pk;
            }
    } else {
        #pragma unroll
        for (int mi = 0; mi < 4; ++mi)
            #pragma unroll
            for (int ni = 0; ni < 4; ++ni) {
                float bias = biasc[n0w + ni*16 + c];
                #pragma unroll
                for (int rg = 0; rg < 4; ++rg)
                    E[(mi*16 + g*4 + rg)*68 + ni*16 + c] = f2bf(acc[mi][ni][rg]+bias);
            }
    }

    const int l = lane;
    if (proj == 0) {
        char* base = (char*)Qb + ((size_t)(bi*HH + h)*64 + (st0 >> 5) + (l >> 5)) * 4096;
        #pragma unroll
        for (int j = 0; j < 8; ++j) {
            uint2 v0 = *(uint2*)&E[l*68 + j*8];
            uint2 v1 = *(uint2*)&E[l*68 + j*8 + 4];
            uint4 v = { v0.x, v0.y, v1.x, v1.y };
            *(uint4*)(base + j*512 + (l & 31)*16) = v;
        }
    } else if (proj == 1) {
        char* base = (char*)Kb + ((size_t)(bi*HH + h)*32 + (st0 >> 6)) * 8192;
        #pragma unroll
        for (int j = 0; j < 8; ++j) {
            uint2 v0 = *(uint2*)&E[l*68 + j*8];
            uint2 v1 = *(uint2*)&E[l*68 + j*8 + 4];
            uint4 v = { v0.x, v0.y, v1.x, v1.y };
            *(uint4*)(base + j*1024 + l*16) = v;
        }
    } else {
        char* base = (char*)Vtb + ((size_t)(bi*HH + h)*32 + (st0 >> 6)) * 8192;
        #pragma unroll
        for (int j = 0; j < 8; ++j) {
            uint2 v0 = *(uint2*)&E[l*68 + j*8];
            uint2 v1 = *(uint2*)&E[l*68 + j*8 + 4];
            uint4 v = { v0.x, v0.y, v1.x, v1.y };
            *(uint4*)(base + j*1024 + l*16) = v;
        }
    }
}

// ---------------------------------------------------------------------------
// Output projection GEMM + bias + residual -> bf16 ybuf via coalesced
// wave-LDS retile epilogue. grid (4, 64).
// ---------------------------------------------------------------------------
__global__ __launch_bounds__(256) void oproj_mm(
    const ushort* __restrict__ ctx, const ushort* __restrict__ wob,
    const float* __restrict__ bo, const float* __restrict__ resid,
    ushort* __restrict__ out)
{
    __shared__ char smem[34816];
    ushort* Abuf = (ushort*)smem;
    ushort* Bbuf = (ushort*)(smem + 16384);

    const int t = threadIdx.x, w = t >> 6, lane = t & 63;
    const int wr = w >> 1, wc = w & 1, c = lane & 15, g = lane >> 4;
    const int nblk = blockIdx.x, mblk = blockIdx.y;

    const ushort* Ag = ctx + (size_t)mblk * 128 * DD;
    const ushort* Bg = wob + (size_t)nblk * 128 * DD;

    f32x4 acc[4][4] = {};

    for (int k0 = 0; k0 < DD; k0 += 64) {
        stage_tile(Ag, k0, Abuf, t);
        stage_tile(Bg, k0, Bbuf, t);
        __syncthreads();
        mma_step(Abuf, Bbuf, wr, wc, c, g, acc);
        __syncthreads();
    }

    ushort* E = (ushort*)(smem + (size_t)w * 8704);
    const int n0w = nblk*128 + wc*64;
    const int m0w = mblk*128 + wr*64;

    #pragma unroll
    for (int mi = 0; mi < 4; ++mi)
        #pragma unroll
        for (int ni = 0; ni < 4; ++ni) {
            float bias = bo[n0w + ni*16 + c];
            #pragma unroll
            for (int rg = 0; rg < 4; ++rg) {
                int mm = m0w + mi*16 + g*4 + rg;
                float val = acc[mi][ni][rg] + bias
                          + resid[(size_t)mm*DD + n0w + ni*16 + c];
                E[(mi*16 + g*4 + rg)*68 + ni*16 + c] = f2bf(val);
            }
        }

    const int l = lane;
    #pragma unroll
    for (int j = 0; j < 8; ++j) {
        int row = j*8 + (l >> 3);
        uint2 v0 = *(uint2*)&E[row*68 + (l & 7)*8];
        uint2 v1 = *(uint2*)&E[row*68 + (l & 7)*8 + 4];
        uint4 v = { v0.x, v0.y, v1.x, v1.y };
        *(uint4*)&out[(size_t)(m0w + row)*DD + n0w + (l & 7)*8] = v;
    }
}

// ---------------------------------------------------------------------------
// Flash attention v9: round-11 pipelined body + DUAL PV ACCUMULATORS
// (otA/otB alternate per tile -> inter-iteration accumulate chains split).
// grid 512 x 512 thr.
// ---------------------------------------------------------------------------
__global__ __launch_bounds__(512, 4) void attn_kernel(
    const ushort* __restrict__ Q, const ushort* __restrict__ K,
    const ushort* __restrict__ Vt, ushort* __restrict__ ctx)
{
    __shared__ ushort Ks[2][2][64*64];    // [kvh][buf2] 32 KB
    __shared__ ushort Vts[2][3][64*64];   // [kvh][buf3] 48 KB

    const int t = threadIdx.x;
    const int w = t >> 6, l = t & 63;
    const int ln31 = l & 31, hi = l >> 5;
    const int qb = w & 3, kvh = w >> 2;

    const int id  = blockIdx.x;
    const int swz = (id & 7) * 64 + (id >> 3);
    const int qt = swz & 15;
    const int h  = (swz >> 4) & 7;
    const int b  = swz >> 7;
    const size_t bh = (size_t)b * HH + h;
    const int q0 = qt*128 + qb*32;

    const char* Qp = (const char*)Q + (bh*64 + (size_t)(qt*4 + qb)) * 4096;
    bf16x8 qf[4];
    #pragma unroll
    for (int s = 0; s < 4; ++s)
        qf[s] = *(const bf16x8*)(Qp + (2*s + hi)*512 + ln31*16);

    const int t2 = t & 255;
    const int NT = 16;
    const size_t kvbase = bh * 32;

#define ATTN_STAGE(kvi, kb_, vb_) do {                                      \
        const size_t tb_ = (kvbase + (size_t)(kvh*NT + (kvi))) * 8192;      \
        const char* kp_ = (const char*)K  + tb_;                            \
        const char* vp_ = (const char*)Vt + tb_;                            \
        gload16(kp_ + t2*16,        (char*)&Ks[kvh][kb_][0] + t2*16);       \
        gload16(kp_ + 4096 + t2*16, (char*)&Ks[kvh][kb_][0] + 4096 + t2*16);\
        gload16(vp_ + t2*16,        (char*)&Vts[kvh][vb_][0] + t2*16);      \
        gload16(vp_ + 4096 + t2*16, (char*)&Vts[kvh][vb_][0] + 4096 + t2*16);\
    } while (0)

#define QKT(kb_, ST) do {                                                   \
        const char* Kc_ = (const char*)&Ks[kvh][kb_][0];                    \
        __builtin_amdgcn_s_setprio(1);                                      \
        _Pragma("unroll")                                                   \
        for (int kt = 0; kt < 2; ++kt) {                                    \
            f32x16 z_ = {};                                                 \
            _Pragma("unroll")                                               \
            for (int s = 0; s < 4; ++s) {                                   \
                bf16x8 kf_ = *(const bf16x8*)(Kc_ + ((2*s + hi) << 10)      \
                                                  + ((kt*32 + ln31) << 4)); \
                z_ = __builtin_amdgcn_mfma_f32_32x32x16_bf16(kf_, qf[s], z_, 0, 0, 0); \
            }                                                               \
            ST[kt] = z_;                                                    \
        }                                                                   \
        __builtin_amdgcn_s_setprio(0);                                      \
    } while (0)

#define PVSTEP(vb_, PB, OT) do {                                            \
        const char* Vc_ = (const char*)&Vts[kvh][vb_][0];                   \
        __builtin_amdgcn_s_setprio(1);                                      \
        _Pragma("unroll")                                                   \
        for (int kt = 0; kt < 2; ++kt)                                      \
            _Pragma("unroll")                                               \
            for (int s2 = 0; s2 < 2; ++s2)                                  \
                _Pragma("unroll")                                           \
                for (int dt = 0; dt < 2; ++dt) {                            \
                    bf16x8 vf_ = *(const bf16x8*)(Vc_ + ((kt*4 + 2*s2 + hi) << 10) \
                                                      + ((dt*32 + ln31) << 4));    \
                    OT[dt] = __builtin_amdgcn_mfma_f32_32x32x16_bf16(vf_, PB[kt][s2], OT[dt], 0, 0, 0); \
                }                                                           \
        __builtin_amdgcn_s_setprio(0);                                      \
    } while (0)

#define SOFTPACK(ST, PB) do {                                               \
        _Pragma("unroll")                                                   \
        for (int kt = 0; kt < 2; ++kt)                                      \
            _Pragma("unroll")                                               \
            for (int i = 0; i < 16; ++i)                                    \
                ST[kt][i] = exp2_hw(ST[kt][i]);                             \
        {                                                                   \
            float ps_[16];                                                  \
            _Pragma("unroll")                                               \
            for (int i = 0; i < 16; ++i) ps_[i] = ST[0][i] + ST[1][i];      \
            _Pragma("unroll")                                               \
            for (int i = 0; i < 8; ++i)  ps_[i] += ps_[i+8];                \
            _Pragma("unroll")                                               \
            for (int i = 0; i < 4; ++i)  ps_[i] += ps_[i+4];                \
            float psum_ = (ps_[0] + ps_[1]) + (ps_[2] + ps_[3]);            \
            float pa_ = psum_, pb2_ = psum_;                                \
            plane_swapf(pa_, pb2_);                                         \
            lsum += pa_ + pb2_;                                             \
        }                                                                   \
        unsigned dk_[2][4][2];                                              \
        _Pragma("unroll")                                                   \
        for (int kt = 0; kt < 2; ++kt)                                      \
            _Pragma("unroll")                                               \
            for (int rb = 0; rb < 4; ++rb) {                                \
                dk_[kt][rb][0] = cvt_pk_bf16(ST[kt][4*rb+0], ST[kt][4*rb+1]);\
                dk_[kt][rb][1] = cvt_pk_bf16(ST[kt][4*rb+2], ST[kt][4*rb+3]);\
            }                                                               \
        _Pragma("unroll")                                                   \
        for (int kt = 0; kt < 2; ++kt)                                      \
            _Pragma("unroll")                                               \
            for (int s2 = 0; s2 < 2; ++s2) {                                \
                unsigned a0_ = dk_[kt][2*s2][0], b0_ = dk_[kt][2*s2+1][0];  \
                unsigned a1_ = dk_[kt][2*s2][1], b1_ = dk_[kt][2*s2+1][1];  \
                plane_swap(a0_, b0_);                                       \
                plane_swap(a1_, b1_);                                       \
                PB[kt][s2] = pack4(a0_, a1_, b0_, b1_);                     \
            }                                                               \
    } while (0)

#define ITER(kv, PBP, PBC, OT) do {                                         \
        __syncthreads();                                                    \
        if ((kv) + 1 < NT) ATTN_STAGE((kv)+1, ((kv)+1)&1, ((kv)+1)%3);      \
        f32x16 stl[2];                                                      \
        QKT((kv)&1, stl);                                                   \
        PVSTEP(((kv)-1)%3, PBP, OT);                                        \
        SOFTPACK(stl, PBC);                                                 \
    } while (0)

    f32x16 otA[2] = {};
    f32x16 otB[2] = {};
    float lsum = 0.f;
    bf16x8 pbA[2][2], pbB[2][2];

    ATTN_STAGE(0, 0, 0);
    __syncthreads();
    ATTN_STAGE(1, 1, 1);
    {
        f32x16 stl[2];
        QKT(0, stl);
        SOFTPACK(stl, pbA);
    }

    for (int kv = 1; kv <= 13; kv += 2) {
        ITER(kv,     pbA, pbB, otA);
        ITER(kv + 1, pbB, pbA, otB);
    }
    ITER(15, pbA, pbB, otA);
    PVSTEP(15 % 3, pbB, otB);              // drain last PV

#undef ITER
#undef SOFTPACK
#undef PVSTEP
#undef QKT
#undef ATTN_STAGE

    f32x16 ot[2];
    ot[0] = otA[0] + otB[0];
    ot[1] = otA[1] + otB[1];

    // ---- intra-block combine of the two kv-halves (additive partials) ----
    __syncthreads();
    float* comb = (float*)&Vts[0][0][0];   // 33792 B needed <= 48 KB
    float* p = comb + (size_t)(qb*64 + l) * 33;
    if (kvh == 0) {
        #pragma unroll
        for (int i = 0; i < 16; ++i) { p[i] = ot[0][i]; p[16+i] = ot[1][i]; }
        p[32] = lsum;
    }
    __syncthreads();
    if (kvh == 1) {
        const float rl = 1.f / (lsum + p[32]);
        ushort* outp = ctx + ((size_t)b*SS + q0 + ln31) * DD + h*DHH;
        #pragma unroll
        for (int dt = 0; dt < 2; ++dt)
            #pragma unroll
            for (int rb = 0; rb < 4; ++rb) {
                ushort4 o = { f2bf((ot[dt][4*rb+0] + p[dt*16+4*rb+0])*rl),
                              f2bf((ot[dt][4*rb+1] + p[dt*16+4*rb+1])*rl),
                              f2bf((ot[dt][4*rb+2] + p[dt*16+4*rb+2])*rl),
                              f2bf((ot[dt][4*rb+3] + p[dt*16+4*rb+3])*rl) };
                *(ushort4*)&outp[dt*32 + rb*8 + hi*4] = o;
            }
    }
}

// ---------------------------------------------------------------------------
// Row LayerNorm (bf16 input, f32 output)
// ---------------------------------------------------------------------------
__global__ __launch_bounds__(256) void ln_kernel(
    const ushort* __restrict__ y, const float* __restrict__ gamma,
    const float* __restrict__ beta, float* __restrict__ out)
{
    const int row = blockIdx.x;
    const int t = threadIdx.x;

    unsigned u = *(const unsigned*)&y[(size_t)row * DD + t*2];
    union { unsigned u; float f; } lo, hi;
    lo.u = (u & 0xFFFFu) << 16;
    hi.u = u & 0xFFFF0000u;
    float2 v = { lo.f, hi.f };

    float s  = v.x + v.y;
    float sq = v.x*v.x + v.y*v.y;
    #pragma unroll
    for (int off = 1; off < 64; off <<= 1) {
        s  += __shfl_xor(s,  off);
        sq += __shfl_xor(sq, off);
    }
    __shared__ float ss[4], ssq[4];
    int wv = t >> 6;
    if ((t & 63) == 0) { ss[wv] = s; ssq[wv] = sq; }
    __syncthreads();
    s  = ss[0] + ss[1] + ss[2] + ss[3];
    sq = ssq[0] + ssq[1] + ssq[2] + ssq[3];

    float mean = s * (1.0f / DD);
    float var  = sq * (1.0f / DD) - mean * mean;
    float rstd = rsqrtf(var + LN_EPS);

    float2 g  = *(const float2*)&gamma[t*2];
    float2 be = *(const float2*)&beta[t*2];
    float2 o;
    o.x = (v.x - mean) * rstd * g.x + be.x;
    o.y = (v.y - mean) * rstd * g.y + be.y;
    *(float2*)&out[(size_t)row * DD + t*2] = o;
}

// ---------------------------------------------------------------------------
extern "C" void kernel_launch(void* const* d_in, const int* in_sizes, int n_in,
                              void* d_out, int out_size, void* d_ws, size_t ws_size,
                              hipStream_t stream)
{
    const float* x     = (const float*)d_in[0];
    const float* wq    = (const float*)d_in[1];
    const float* bq    = (const float*)d_in[2];
    const float* wk    = (const float*)d_in[3];
    const float* bk    = (const float*)d_in[4];
    const float* wv    = (const float*)d_in[5];
    const float* bv    = (const float*)d_in[6];
    const float* wo    = (const float*)d_in[7];
    const float* bo    = (const float*)d_in[8];
    const float* gamma = (const float*)d_in[9];
    const float* beta  = (const float*)d_in[10];

    char* wsb = (char*)d_ws;
    const size_t MB = 1u << 20;
    ushort* ybuf  = (ushort*)(wsb + 0*MB);    // 8 MB bf16
    ushort* wb    = (ushort*)(wsb + 8*MB);    // 2 MB
    float*  biasc = (float* )(wsb + 10*MB);   // 6 KB
    ushort* Qb    = (ushort*)(wsb + 11*MB);   // fragment-major
    ushort* Kb    = (ushort*)(wsb + 19*MB);   // fragment-major
    ushort* Vtb   = (ushort*)(wsb + 27*MB);   // fragment-major transposed
    ushort* ctxb  = (ushort*)(wsb + 35*MB);

    wcast_kernel<<<512, 256, 0, stream>>>(wq, wk, wv, wo, bq, bk, bv, wb, biasc);
    {
        dim3 grid(12, 64);
        qkv_mm<<<grid, 256, 0, stream>>>(x, wb, biasc, Qb, Kb, Vtb);
    }
    {
        attn_kernel<<<512, 512, 0, stream>>>(Qb, Kb, Vtb, ctxb);
    }
    {
        dim3 grid(4, 64);
        oproj_mm<<<grid, 256, 0, stream>>>(ctxb, wb + 3*DD*DD, bo, x, ybuf);
    }
    ln_kernel<<<MROWS, 256, 0, stream>>>(ybuf, gamma, beta, (float*)d_out);
}

// Round 13
// 105.601 us; speedup vs baseline: 1.8726x; 1.8726x over previous
//
#include <hip/hip_runtime.h>
#include <hip/hip_bf16.h>
#include <math.h>

#define BB 4
#define SS 2048
#define DD 512
#define HH 8
#define DHH 64
#define MROWS (BB*SS)

constexpr float SCALE  = 0.044194173824159216f;            // 1/sqrt(512)
constexpr float QSCALE = (float)(0.044194173824159216 * 1.4426950408889634); // SCALE*log2(e)
constexpr float LN_EPS = 1e-5f;

typedef __attribute__((ext_vector_type(8)))  short bf16x8;
typedef __attribute__((ext_vector_type(4)))  float f32x4;
typedef __attribute__((ext_vector_type(16))) float f32x16;

__device__ __forceinline__ ushort f2bf(float f) {
    __hip_bfloat16 h = __float2bfloat16(f);
    ushort u; __builtin_memcpy(&u, &h, 2);
    return u;
}

__device__ __forceinline__ float exp2_hw(float x) {
#if __has_builtin(__builtin_amdgcn_exp2f)
    return __builtin_amdgcn_exp2f(x);
#else
    return exp2f(x);
#endif
}

__device__ __forceinline__ unsigned cvt_pk_bf16(float lo, float hi) {
    unsigned r;
    asm("v_cvt_pk_bf16_f32 %0, %1, %2" : "=v"(r) : "v"(lo), "v"(hi));
    return r;
}
__device__ __forceinline__ void plane_swap(unsigned &a, unsigned &b) {
    asm("v_permlane32_swap_b32 %0, %1" : "+v"(a), "+v"(b));
}
__device__ __forceinline__ void plane_swapf(float &a, float &b) {
    asm("v_permlane32_swap_b32 %0, %1" : "+v"(a), "+v"(b));
}
__device__ __forceinline__ bf16x8 pack4(unsigned a0, unsigned a1, unsigned b0, unsigned b1) {
    union { unsigned u[4]; bf16x8 v; } x;
    x.u[0] = a0; x.u[1] = a1; x.u[2] = b0; x.u[3] = b1;
    return x.v;
}

__device__ __forceinline__ void gload16(const void* gsrc, void* lds_dst) {
    __builtin_amdgcn_global_load_lds(
        (const __attribute__((address_space(1))) unsigned int*)gsrc,
        (__attribute__((address_space(3))) unsigned int*)lds_dst,
        16, 0, 0);
}

// ---------------------------------------------------------------------------
// Weight cast/pack only: wb = bf16([wq*QS; wk; wv; wo]); biasc = [bq*QS,bk,bv]
// grid 512, block 256
// ---------------------------------------------------------------------------
__global__ __launch_bounds__(256) void wcast_kernel(
    const float* __restrict__ wq, const float* __restrict__ wk,
    const float* __restrict__ wv, const float* __restrict__ wo,
    const float* __restrict__ bq, const float* __restrict__ bk,
    const float* __restrict__ bv,
    ushort* __restrict__ wb, float* __restrict__ biasc)
{
    const int gid = blockIdx.x * 256 + threadIdx.x;
    if (gid < 1536) {
        float v = gid < 512 ? bq[gid] * QSCALE
                : gid < 1024 ? bk[gid - 512] : bv[gid - 1024];
        biasc[gid] = v;
    }
    const int NW4 = (DD * DD) / 4;        // 65536
    for (int j = gid; j < 4 * NW4; j += gridDim.x * 256) {
        int which = j >> 16;
        int off = j & 65535;
        const float4* src = which == 0 ? (const float4*)wq
                          : which == 1 ? (const float4*)wk
                          : which == 2 ? (const float4*)wv : (const float4*)wo;
        float4 v = src[off];
        float scl = which == 0 ? QSCALE : 1.0f;
        ushort4 o = { f2bf(v.x * scl), f2bf(v.y * scl),
                      f2bf(v.z * scl), f2bf(v.w * scl) };
        ((ushort4*)wb)[j] = o;
    }
}

// ---------------------------------------------------------------------------
// Shared GEMM-BT machinery (validated rounds 2-12)
// ---------------------------------------------------------------------------
__device__ __forceinline__ void stage_tile(const ushort* __restrict__ g, int k0,
                                           ushort* lbuf, int t)
{
    #pragma unroll
    for (int i = 0; i < 4; ++i) {
        int cc = i * 256 + t;
        int row = cc >> 3, slot = cc & 7;
        gload16(g + row * DD + k0 + ((slot ^ (row & 7)) << 3), lbuf + cc * 8);
    }
}

// f32 source variant with inline bf16 convert (per-lane ds_write, rule #21 ok)
__device__ __forceinline__ void stage_xtile(const float* __restrict__ g, int k0,
                                            ushort* lbuf, int t)
{
    #pragma unroll
    for (int i = 0; i < 4; ++i) {
        int cc = i * 256 + t;
        int row = cc >> 3, slot = cc & 7;
        const float* src = g + (size_t)row * DD + k0 + ((slot ^ (row & 7)) << 3);
        float4 a = *(const float4*)src;
        float4 b = *(const float4*)(src + 4);
        uint4 v = { cvt_pk_bf16(a.x, a.y), cvt_pk_bf16(a.z, a.w),
                    cvt_pk_bf16(b.x, b.y), cvt_pk_bf16(b.z, b.w) };
        *(uint4*)(lbuf + cc * 8) = v;
    }
}

__device__ __forceinline__ void mma_step(const ushort* Abuf, const ushort* Bbuf,
                                         int wr, int wc, int c, int g,
                                         f32x4 (&acc)[4][4])
{
    bf16x8 af[2][4], bf[2][4];
    #pragma unroll
    for (int kc = 0; kc < 2; ++kc) {
        int sw = ((kc * 4 + g) ^ (c & 7)) << 4;
        #pragma unroll
        for (int mi = 0; mi < 4; ++mi)
            af[kc][mi] = *(const bf16x8*)((const char*)Abuf + (wr*64 + mi*16 + c)*128 + sw);
        #pragma unroll
        for (int ni = 0; ni < 4; ++ni)
            bf[kc][ni] = *(const bf16x8*)((const char*)Bbuf + (wc*64 + ni*16 + c)*128 + sw);
    }
    __builtin_amdgcn_s_setprio(1);
    #pragma unroll
    for (int kc = 0; kc < 2; ++kc)
        #pragma unroll
        for (int mi = 0; mi < 4; ++mi)
            #pragma unroll
            for (int ni = 0; ni < 4; ++ni)
                acc[mi][ni] = __builtin_amdgcn_mfma_f32_16x16x32_bf16(
                    af[kc][mi], bf[kc][ni], acc[mi][ni], 0, 0, 0);
    __builtin_amdgcn_s_setprio(0);
}

// ---------------------------------------------------------------------------
// QKV projection GEMM. grid (12, 64). A staged from f32 x with inline cvt.
// Coalesced fragment-major epilogue.
//  Q: [bh][q/32][d/8][q%32][8]   K: [bh][s/64][d/8][s%64][8]
//  V: [bh][s/64][(s%64)/8][d][8] (transposed)
// ---------------------------------------------------------------------------
__global__ __launch_bounds__(256) void qkv_mm(
    const float* __restrict__ x, const ushort* __restrict__ wb,
    const float* __restrict__ biasc,
    ushort* __restrict__ Qb, ushort* __restrict__ Kb, ushort* __restrict__ Vtb)
{
    __shared__ char smem[34816];            // Abuf16K + Bbuf16K; epi 4x8704
    ushort* Abuf = (ushort*)smem;
    ushort* Bbuf = (ushort*)(smem + 16384);

    const int t = threadIdx.x, w = t >> 6, lane = t & 63;
    const int wr = w >> 1, wc = w & 1, c = lane & 15, g = lane >> 4;
    const int nblk = blockIdx.x, mblk = blockIdx.y;

    const float*  Ag = x  + (size_t)mblk * 128 * DD;
    const ushort* Bg = wb + (size_t)nblk * 128 * DD;

    f32x4 acc[4][4] = {};

    for (int k0 = 0; k0 < DD; k0 += 64) {
        stage_xtile(Ag, k0, Abuf, t);
        stage_tile(Bg, k0, Bbuf, t);
        __syncthreads();
        mma_step(Abuf, Bbuf, wr, wc, c, g, acc);
        __syncthreads();                    // frees Abuf/Bbuf for epilogue
    }

    // ---- wave-private LDS retile (stride 68 ushorts) ----
    ushort* E = (ushort*)(smem + (size_t)w * 8704);
    const int n0w  = nblk*128 + wc*64;
    const int proj = n0w >> 9;
    const int h    = (n0w & 511) >> 6;
    const int m0w  = mblk*128 + wr*64;
    const int bi   = m0w >> 11;
    const int st0  = m0w & 2047;

    if (proj == 2) {
        #pragma unroll
        for (int mi = 0; mi < 4; ++mi)
            #pragma unroll
            for (int ni = 0; ni < 4; ++ni) {
                float bias = biasc[n0w + ni*16 + c];
                ushort4 pk = { f2bf(acc[mi][ni][0]+bias), f2bf(acc[mi][ni][1]+bias),
                               f2bf(acc[mi][ni][2]+bias), f2bf(acc[mi][ni][3]+bias) };
                *(ushort4*)&E[(ni*16 + c)*68 + mi*16 + g*4] = pk;
            }
    } else {
        #pragma unroll
        for (int mi = 0; mi < 4; ++mi)
            #pragma unroll
            for (int ni = 0; ni < 4; ++ni) {
                float bias = biasc[n0w + ni*16 + c];
                #pragma unroll
                for (int rg = 0; rg < 4; ++rg)
                    E[(mi*16 + g*4 + rg)*68 + ni*16 + c] = f2bf(acc[mi][ni][rg]+bias);
            }
    }

    const int l = lane;
    if (proj == 0) {
        char* base = (char*)Qb + ((size_t)(bi*HH + h)*64 + (st0 >> 5) + (l >> 5)) * 4096;
        #pragma unroll
        for (int j = 0; j < 8; ++j) {
            uint2 v0 = *(uint2*)&E[l*68 + j*8];
            uint2 v1 = *(uint2*)&E[l*68 + j*8 + 4];
            uint4 v = { v0.x, v0.y, v1.x, v1.y };
            *(uint4*)(base + j*512 + (l & 31)*16) = v;
        }
    } else if (proj == 1) {
        char* base = (char*)Kb + ((size_t)(bi*HH + h)*32 + (st0 >> 6)) * 8192;
        #pragma unroll
        for (int j = 0; j < 8; ++j) {
            uint2 v0 = *(uint2*)&E[l*68 + j*8];
            uint2 v1 = *(uint2*)&E[l*68 + j*8 + 4];
            uint4 v = { v0.x, v0.y, v1.x, v1.y };
            *(uint4*)(base + j*1024 + l*16) = v;
        }
    } else {
        char* base = (char*)Vtb + ((size_t)(bi*HH + h)*32 + (st0 >> 6)) * 8192;
        #pragma unroll
        for (int j = 0; j < 8; ++j) {
            uint2 v0 = *(uint2*)&E[l*68 + j*8];
            uint2 v1 = *(uint2*)&E[l*68 + j*8 + 4];
            uint4 v = { v0.x, v0.y, v1.x, v1.y };
            *(uint4*)(base + j*1024 + l*16) = v;
        }
    }
}

// ---------------------------------------------------------------------------
// Output projection GEMM + bias + residual -> bf16 ybuf via coalesced
// wave-LDS retile epilogue. grid (4, 64).
// ---------------------------------------------------------------------------
__global__ __launch_bounds__(256) void oproj_mm(
    const ushort* __restrict__ ctx, const ushort* __restrict__ wob,
    const float* __restrict__ bo, const float* __restrict__ resid,
    ushort* __restrict__ out)
{
    __shared__ char smem[34816];
    ushort* Abuf = (ushort*)smem;
    ushort* Bbuf = (ushort*)(smem + 16384);

    const int t = threadIdx.x, w = t >> 6, lane = t & 63;
    const int wr = w >> 1, wc = w & 1, c = lane & 15, g = lane >> 4;
    const int nblk = blockIdx.x, mblk = blockIdx.y;

    const ushort* Ag = ctx + (size_t)mblk * 128 * DD;
    const ushort* Bg = wob + (size_t)nblk * 128 * DD;

    f32x4 acc[4][4] = {};

    for (int k0 = 0; k0 < DD; k0 += 64) {
        stage_tile(Ag, k0, Abuf, t);
        stage_tile(Bg, k0, Bbuf, t);
        __syncthreads();
        mma_step(Abuf, Bbuf, wr, wc, c, g, acc);
        __syncthreads();
    }

    ushort* E = (ushort*)(smem + (size_t)w * 8704);
    const int n0w = nblk*128 + wc*64;
    const int m0w = mblk*128 + wr*64;

    #pragma unroll
    for (int mi = 0; mi < 4; ++mi)
        #pragma unroll
        for (int ni = 0; ni < 4; ++ni) {
            float bias = bo[n0w + ni*16 + c];
            #pragma unroll
            for (int rg = 0; rg < 4; ++rg) {
                int mm = m0w + mi*16 + g*4 + rg;
                float val = acc[mi][ni][rg] + bias
                          + resid[(size_t)mm*DD + n0w + ni*16 + c];
                E[(mi*16 + g*4 + rg)*68 + ni*16 + c] = f2bf(val);
            }
        }

    const int l = lane;
    #pragma unroll
    for (int j = 0; j < 8; ++j) {
        int row = j*8 + (l >> 3);
        uint2 v0 = *(uint2*)&E[row*68 + (l & 7)*8];
        uint2 v1 = *(uint2*)&E[row*68 + (l & 7)*8 + 4];
        uint4 v = { v0.x, v0.y, v1.x, v1.y };
        *(uint4*)&out[(size_t)(m0w + row)*DD + n0w + (l & 7)*8] = v;
    }
}

// ---------------------------------------------------------------------------
// Flash attention v10 = round-11 validated body (single ot accumulator --
// the round-12 dual-accumulator spilled to scratch and 3x'd runtime),
// combine buffer on Vts. grid 512 x 512 thr.
// ---------------------------------------------------------------------------
__global__ __launch_bounds__(512, 4) void attn_kernel(
    const ushort* __restrict__ Q, const ushort* __restrict__ K,
    const ushort* __restrict__ Vt, ushort* __restrict__ ctx)
{
    __shared__ ushort Ks[2][2][64*64];    // [kvh][buf2] 32 KB
    __shared__ ushort Vts[2][3][64*64];   // [kvh][buf3] 48 KB

    const int t = threadIdx.x;
    const int w = t >> 6, l = t & 63;
    const int ln31 = l & 31, hi = l >> 5;
    const int qb = w & 3, kvh = w >> 2;

    const int id  = blockIdx.x;
    const int swz = (id & 7) * 64 + (id >> 3);
    const int qt = swz & 15;
    const int h  = (swz >> 4) & 7;
    const int b  = swz >> 7;
    const size_t bh = (size_t)b * HH + h;
    const int q0 = qt*128 + qb*32;

    const char* Qp = (const char*)Q + (bh*64 + (size_t)(qt*4 + qb)) * 4096;
    bf16x8 qf[4];
    #pragma unroll
    for (int s = 0; s < 4; ++s)
        qf[s] = *(const bf16x8*)(Qp + (2*s + hi)*512 + ln31*16);

    const int t2 = t & 255;
    const int NT = 16;
    const size_t kvbase = bh * 32;

#define ATTN_STAGE(kvi, kb_, vb_) do {                                      \
        const size_t tb_ = (kvbase + (size_t)(kvh*NT + (kvi))) * 8192;      \
        const char* kp_ = (const char*)K  + tb_;                            \
        const char* vp_ = (const char*)Vt + tb_;                            \
        gload16(kp_ + t2*16,        (char*)&Ks[kvh][kb_][0] + t2*16);       \
        gload16(kp_ + 4096 + t2*16, (char*)&Ks[kvh][kb_][0] + 4096 + t2*16);\
        gload16(vp_ + t2*16,        (char*)&Vts[kvh][vb_][0] + t2*16);      \
        gload16(vp_ + 4096 + t2*16, (char*)&Vts[kvh][vb_][0] + 4096 + t2*16);\
    } while (0)

#define QKT(kb_, ST) do {                                                   \
        const char* Kc_ = (const char*)&Ks[kvh][kb_][0];                    \
        __builtin_amdgcn_s_setprio(1);                                      \
        _Pragma("unroll")                                                   \
        for (int kt = 0; kt < 2; ++kt) {                                    \
            f32x16 z_ = {};                                                 \
            _Pragma("unroll")                                               \
            for (int s = 0; s < 4; ++s) {                                   \
                bf16x8 kf_ = *(const bf16x8*)(Kc_ + ((2*s + hi) << 10)      \
                                                  + ((kt*32 + ln31) << 4)); \
                z_ = __builtin_amdgcn_mfma_f32_32x32x16_bf16(kf_, qf[s], z_, 0, 0, 0); \
            }                                                               \
            ST[kt] = z_;                                                    \
        }                                                                   \
        __builtin_amdgcn_s_setprio(0);                                      \
    } while (0)

#define PVSTEP(vb_, PB) do {                                                \
        const char* Vc_ = (const char*)&Vts[kvh][vb_][0];                   \
        __builtin_amdgcn_s_setprio(1);                                      \
        _Pragma("unroll")                                                   \
        for (int kt = 0; kt < 2; ++kt)                                      \
            _Pragma("unroll")                                               \
            for (int s2 = 0; s2 < 2; ++s2)                                  \
                _Pragma("unroll")                                           \
                for (int dt = 0; dt < 2; ++dt) {                            \
                    bf16x8 vf_ = *(const bf16x8*)(Vc_ + ((kt*4 + 2*s2 + hi) << 10) \
                                                      + ((dt*32 + ln31) << 4));    \
                    ot[dt] = __builtin_amdgcn_mfma_f32_32x32x16_bf16(vf_, PB[kt][s2], ot[dt], 0, 0, 0); \
                }                                                           \
        __builtin_amdgcn_s_setprio(0);                                      \
    } while (0)

#define SOFTPACK(ST, PB) do {                                               \
        _Pragma("unroll")                                                   \
        for (int kt = 0; kt < 2; ++kt)                                      \
            _Pragma("unroll")                                               \
            for (int i = 0; i < 16; ++i)                                    \
                ST[kt][i] = exp2_hw(ST[kt][i]);                             \
        {                                                                   \
            float ps_[16];                                                  \
            _Pragma("unroll")                                               \
            for (int i = 0; i < 16; ++i) ps_[i] = ST[0][i] + ST[1][i];      \
            _Pragma("unroll")                                               \
            for (int i = 0; i < 8; ++i)  ps_[i] += ps_[i+8];                \
            _Pragma("unroll")                                               \
            for (int i = 0; i < 4; ++i)  ps_[i] += ps_[i+4];                \
            float psum_ = (ps_[0] + ps_[1]) + (ps_[2] + ps_[3]);            \
            float pa_ = psum_, pb2_ = psum_;                                \
            plane_swapf(pa_, pb2_);                                         \
            lsum += pa_ + pb2_;                                             \
        }                                                                   \
        unsigned dk_[2][4][2];                                              \
        _Pragma("unroll")                                                   \
        for (int kt = 0; kt < 2; ++kt)                                      \
            _Pragma("unroll")                                               \
            for (int rb = 0; rb < 4; ++rb) {                                \
                dk_[kt][rb][0] = cvt_pk_bf16(ST[kt][4*rb+0], ST[kt][4*rb+1]);\
                dk_[kt][rb][1] = cvt_pk_bf16(ST[kt][4*rb+2], ST[kt][4*rb+3]);\
            }                                                               \
        _Pragma("unroll")                                                   \
        for (int kt = 0; kt < 2; ++kt)                                      \
            _Pragma("unroll")                                               \
            for (int s2 = 0; s2 < 2; ++s2) {                                \
                unsigned a0_ = dk_[kt][2*s2][0], b0_ = dk_[kt][2*s2+1][0];  \
                unsigned a1_ = dk_[kt][2*s2][1], b1_ = dk_[kt][2*s2+1][1];  \
                plane_swap(a0_, b0_);                                       \
                plane_swap(a1_, b1_);                                       \
                PB[kt][s2] = pack4(a0_, a1_, b0_, b1_);                     \
            }                                                               \
    } while (0)

#define ITER(kv, PBP, PBC) do {                                             \
        __syncthreads();                                                    \
        if ((kv) + 1 < NT) ATTN_STAGE((kv)+1, ((kv)+1)&1, ((kv)+1)%3);      \
        f32x16 stl[2];                                                      \
        QKT((kv)&1, stl);                                                   \
        PVSTEP(((kv)-1)%3, PBP);                                            \
        SOFTPACK(stl, PBC);                                                 \
    } while (0)

    f32x16 ot[2] = {};
    float lsum = 0.f;
    bf16x8 pbA[2][2], pbB[2][2];

    // prologue: peel kv = 0 (no PV yet)
    ATTN_STAGE(0, 0, 0);
    __syncthreads();
    ATTN_STAGE(1, 1, 1);
    {
        f32x16 stl[2];
        QKT(0, stl);
        SOFTPACK(stl, pbA);
    }

    for (int kv = 1; kv <= 13; kv += 2) {
        ITER(kv,     pbA, pbB);
        ITER(kv + 1, pbB, pbA);
    }
    ITER(15, pbA, pbB);
    PVSTEP(15 % 3, pbB);                   // drain last PV

#undef ITER
#undef SOFTPACK
#undef PVSTEP
#undef QKT
#undef ATTN_STAGE

    // ---- intra-block combine of the two kv-halves (additive partials) ----
    __syncthreads();
    float* comb = (float*)&Vts[0][0][0];   // 33792 B needed <= 48 KB
    float* p = comb + (size_t)(qb*64 + l) * 33;
    if (kvh == 0) {
        #pragma unroll
        for (int i = 0; i < 16; ++i) { p[i] = ot[0][i]; p[16+i] = ot[1][i]; }
        p[32] = lsum;
    }
    __syncthreads();
    if (kvh == 1) {
        const float rl = 1.f / (lsum + p[32]);
        ushort* outp = ctx + ((size_t)b*SS + q0 + ln31) * DD + h*DHH;
        #pragma unroll
        for (int dt = 0; dt < 2; ++dt)
            #pragma unroll
            for (int rb = 0; rb < 4; ++rb) {
                ushort4 o = { f2bf((ot[dt][4*rb+0] + p[dt*16+4*rb+0])*rl),
                              f2bf((ot[dt][4*rb+1] + p[dt*16+4*rb+1])*rl),
                              f2bf((ot[dt][4*rb+2] + p[dt*16+4*rb+2])*rl),
                              f2bf((ot[dt][4*rb+3] + p[dt*16+4*rb+3])*rl) };
                *(ushort4*)&outp[dt*32 + rb*8 + hi*4] = o;
            }
    }
}

// ---------------------------------------------------------------------------
// Row LayerNorm (bf16 input, f32 output)
// ---------------------------------------------------------------------------
__global__ __launch_bounds__(256) void ln_kernel(
    const ushort* __restrict__ y, const float* __restrict__ gamma,
    const float* __restrict__ beta, float* __restrict__ out)
{
    const int row = blockIdx.x;
    const int t = threadIdx.x;

    unsigned u = *(const unsigned*)&y[(size_t)row * DD + t*2];
    union { unsigned u; float f; } lo, hi;
    lo.u = (u & 0xFFFFu) << 16;
    hi.u = u & 0xFFFF0000u;
    float2 v = { lo.f, hi.f };

    float s  = v.x + v.y;
    float sq = v.x*v.x + v.y*v.y;
    #pragma unroll
    for (int off = 1; off < 64; off <<= 1) {
        s  += __shfl_xor(s,  off);
        sq += __shfl_xor(sq, off);
    }
    __shared__ float ss[4], ssq[4];
    int wv = t >> 6;
    if ((t & 63) == 0) { ss[wv] = s; ssq[wv] = sq; }
    __syncthreads();
    s  = ss[0] + ss[1] + ss[2] + ss[3];
    sq = ssq[0] + ssq[1] + ssq[2] + ssq[3];

    float mean = s * (1.0f / DD);
    float var  = sq * (1.0f / DD) - mean * mean;
    float rstd = rsqrtf(var + LN_EPS);

    float2 g  = *(const float2*)&gamma[t*2];
    float2 be = *(const float2*)&beta[t*2];
    float2 o;
    o.x = (v.x - mean) * rstd * g.x + be.x;
    o.y = (v.y - mean) * rstd * g.y + be.y;
    *(float2*)&out[(size_t)row * DD + t*2] = o;
}

// ---------------------------------------------------------------------------
extern "C" void kernel_launch(void* const* d_in, const int* in_sizes, int n_in,
                              void* d_out, int out_size, void* d_ws, size_t ws_size,
                              hipStream_t stream)
{
    const float* x     = (const float*)d_in[0];
    const float* wq    = (const float*)d_in[1];
    const float* bq    = (const float*)d_in[2];
    const float* wk    = (const float*)d_in[3];
    const float* bk    = (const float*)d_in[4];
    const float* wv    = (const float*)d_in[5];
    const float* bv    = (const float*)d_in[6];
    const float* wo    = (const float*)d_in[7];
    const float* bo    = (const float*)d_in[8];
    const float* gamma = (const float*)d_in[9];
    const float* beta  = (const float*)d_in[10];

    char* wsb = (char*)d_ws;
    const size_t MB = 1u << 20;
    ushort* ybuf  = (ushort*)(wsb + 0*MB);    // 8 MB bf16
    ushort* wb    = (ushort*)(wsb + 8*MB);    // 2 MB
    float*  biasc = (float* )(wsb + 10*MB);   // 6 KB
    ushort* Qb    = (ushort*)(wsb + 11*MB);   // fragment-major
    ushort* Kb    = (ushort*)(wsb + 19*MB);   // fragment-major
    ushort* Vtb   = (ushort*)(wsb + 27*MB);   // fragment-major transposed
    ushort* ctxb  = (ushort*)(wsb + 35*MB);

    wcast_kernel<<<512, 256, 0, stream>>>(wq, wk, wv, wo, bq, bk, bv, wb, biasc);
    {
        dim3 grid(12, 64);
        qkv_mm<<<grid, 256, 0, stream>>>(x, wb, biasc, Qb, Kb, Vtb);
    }
    {
        attn_kernel<<<512, 512, 0, stream>>>(Qb, Kb, Vtb, ctxb);
    }
    {
        dim3 grid(4, 64);
        oproj_mm<<<grid, 256, 0, stream>>>(ctxb, wb + 3*DD*DD, bo, x, ybuf);
    }
    ln_kernel<<<MROWS, 256, 0, stream>>>(ybuf, gamma, beta, (float*)d_out);
}

// Round 14
// 102.136 us; speedup vs baseline: 1.9362x; 1.0339x over previous
//
#include <hip/hip_runtime.h>
#include <hip/hip_bf16.h>
#include <math.h>

#define BB 4
#define SS 2048
#define DD 512
#define HH 8
#define DHH 64
#define MROWS (BB*SS)

constexpr float SCALE  = 0.044194173824159216f;            // 1/sqrt(512)
constexpr float QSCALE = (float)(0.044194173824159216 * 1.4426950408889634); // SCALE*log2(e)
constexpr float LN_EPS = 1e-5f;

typedef __attribute__((ext_vector_type(8)))  short bf16x8;
typedef __attribute__((ext_vector_type(4)))  float f32x4;
typedef __attribute__((ext_vector_type(16))) float f32x16;

__device__ __forceinline__ ushort f2bf(float f) {
    __hip_bfloat16 h = __float2bfloat16(f);
    ushort u; __builtin_memcpy(&u, &h, 2);
    return u;
}

__device__ __forceinline__ float exp2_hw(float x) {
#if __has_builtin(__builtin_amdgcn_exp2f)
    return __builtin_amdgcn_exp2f(x);
#else
    return exp2f(x);
#endif
}

__device__ __forceinline__ unsigned cvt_pk_bf16(float lo, float hi) {
    unsigned r;
    asm("v_cvt_pk_bf16_f32 %0, %1, %2" : "=v"(r) : "v"(lo), "v"(hi));
    return r;
}
__device__ __forceinline__ void plane_swap(unsigned &a, unsigned &b) {
    asm("v_permlane32_swap_b32 %0, %1" : "+v"(a), "+v"(b));
}
__device__ __forceinline__ void plane_swapf(float &a, float &b) {
    asm("v_permlane32_swap_b32 %0, %1" : "+v"(a), "+v"(b));
}
__device__ __forceinline__ bf16x8 pack4(unsigned a0, unsigned a1, unsigned b0, unsigned b1) {
    union { unsigned u[4]; bf16x8 v; } x;
    x.u[0] = a0; x.u[1] = a1; x.u[2] = b0; x.u[3] = b1;
    return x.v;
}

__device__ __forceinline__ void gload16(const void* gsrc, void* lds_dst) {
    __builtin_amdgcn_global_load_lds(
        (const __attribute__((address_space(1))) unsigned int*)gsrc,
        (__attribute__((address_space(3))) unsigned int*)lds_dst,
        16, 0, 0);
}

// ---------------------------------------------------------------------------
// Weight cast/pack only: wb = bf16([wq*QS; wk; wv; wo]); biasc = [bq*QS,bk,bv]
// grid 512, block 256
// ---------------------------------------------------------------------------
__global__ __launch_bounds__(256) void wcast_kernel(
    const float* __restrict__ wq, const float* __restrict__ wk,
    const float* __restrict__ wv, const float* __restrict__ wo,
    const float* __restrict__ bq, const float* __restrict__ bk,
    const float* __restrict__ bv,
    ushort* __restrict__ wb, float* __restrict__ biasc)
{
    const int gid = blockIdx.x * 256 + threadIdx.x;
    if (gid < 1536) {
        float v = gid < 512 ? bq[gid] * QSCALE
                : gid < 1024 ? bk[gid - 512] : bv[gid - 1024];
        biasc[gid] = v;
    }
    const int NW4 = (DD * DD) / 4;        // 65536
    for (int j = gid; j < 4 * NW4; j += gridDim.x * 256) {
        int which = j >> 16;
        int off = j & 65535;
        const float4* src = which == 0 ? (const float4*)wq
                          : which == 1 ? (const float4*)wk
                          : which == 2 ? (const float4*)wv : (const float4*)wo;
        float4 v = src[off];
        float scl = which == 0 ? QSCALE : 1.0f;
        ushort4 o = { f2bf(v.x * scl), f2bf(v.y * scl),
                      f2bf(v.z * scl), f2bf(v.w * scl) };
        ((ushort4*)wb)[j] = o;
    }
}

// ---------------------------------------------------------------------------
// Shared GEMM-BT machinery (validated rounds 2-13)
// ---------------------------------------------------------------------------
__device__ __forceinline__ void stage_tile(const ushort* __restrict__ g, int k0,
                                           ushort* lbuf, int t)
{
    #pragma unroll
    for (int i = 0; i < 4; ++i) {
        int cc = i * 256 + t;
        int row = cc >> 3, slot = cc & 7;
        gload16(g + row * DD + k0 + ((slot ^ (row & 7)) << 3), lbuf + cc * 8);
    }
}

// f32 source variant with inline bf16 convert (per-lane ds_write, rule #21 ok)
__device__ __forceinline__ void stage_xtile(const float* __restrict__ g, int k0,
                                            ushort* lbuf, int t)
{
    #pragma unroll
    for (int i = 0; i < 4; ++i) {
        int cc = i * 256 + t;
        int row = cc >> 3, slot = cc & 7;
        const float* src = g + (size_t)row * DD + k0 + ((slot ^ (row & 7)) << 3);
        float4 a = *(const float4*)src;
        float4 b = *(const float4*)(src + 4);
        uint4 v = { cvt_pk_bf16(a.x, a.y), cvt_pk_bf16(a.z, a.w),
                    cvt_pk_bf16(b.x, b.y), cvt_pk_bf16(b.z, b.w) };
        *(uint4*)(lbuf + cc * 8) = v;
    }
}

__device__ __forceinline__ void mma_step(const ushort* Abuf, const ushort* Bbuf,
                                         int wr, int wc, int c, int g,
                                         f32x4 (&acc)[4][4])
{
    bf16x8 af[2][4], bf[2][4];
    #pragma unroll
    for (int kc = 0; kc < 2; ++kc) {
        int sw = ((kc * 4 + g) ^ (c & 7)) << 4;
        #pragma unroll
        for (int mi = 0; mi < 4; ++mi)
            af[kc][mi] = *(const bf16x8*)((const char*)Abuf + (wr*64 + mi*16 + c)*128 + sw);
        #pragma unroll
        for (int ni = 0; ni < 4; ++ni)
            bf[kc][ni] = *(const bf16x8*)((const char*)Bbuf + (wc*64 + ni*16 + c)*128 + sw);
    }
    __builtin_amdgcn_s_setprio(1);
    #pragma unroll
    for (int kc = 0; kc < 2; ++kc)
        #pragma unroll
        for (int mi = 0; mi < 4; ++mi)
            #pragma unroll
            for (int ni = 0; ni < 4; ++ni)
                acc[mi][ni] = __builtin_amdgcn_mfma_f32_16x16x32_bf16(
                    af[kc][mi], bf[kc][ni], acc[mi][ni], 0, 0, 0);
    __builtin_amdgcn_s_setprio(0);
}

// ---------------------------------------------------------------------------
// QKV projection GEMM. 1D grid 768, XCD-CONTIGUOUS mapping: XCD i gets 96
// consecutive work ids = 8 m-panels x all 12 n-blocks, so each x-panel is
// fetched into ONE XCD L2 (4 MB working set fits). B staged async first,
// then A (f32 -> inline cvt) overlaps B's flight. Coalesced frag-major epi.
//  Q: [bh][q/32][d/8][q%32][8]   K: [bh][s/64][d/8][s%64][8]
//  V: [bh][s/64][(s%64)/8][d][8] (transposed)
// ---------------------------------------------------------------------------
__global__ __launch_bounds__(256) void qkv_mm(
    const float* __restrict__ x, const ushort* __restrict__ wb,
    const float* __restrict__ biasc,
    ushort* __restrict__ Qb, ushort* __restrict__ Kb, ushort* __restrict__ Vtb)
{
    __shared__ char smem[34816];            // Abuf16K + Bbuf16K; epi 4x8704
    ushort* Abuf = (ushort*)smem;
    ushort* Bbuf = (ushort*)(smem + 16384);

    const int t = threadIdx.x, w = t >> 6, lane = t & 63;
    const int wr = w >> 1, wc = w & 1, c = lane & 15, g = lane >> 4;

    // XCD-contiguous: 768 = 8 XCDs x 96; swz groups one XCD's ids so that
    // 8 m-panels x 12 n-blocks share that XCD's L2.
    const int id   = blockIdx.x;
    const int swz  = (id & 7) * 96 + (id >> 3);
    const int mblk = swz / 12;
    const int nblk = swz % 12;

    const float*  Ag = x  + (size_t)mblk * 128 * DD;
    const ushort* Bg = wb + (size_t)nblk * 128 * DD;

    f32x4 acc[4][4] = {};

    for (int k0 = 0; k0 < DD; k0 += 64) {
        stage_tile(Bg, k0, Bbuf, t);        // async B first
        stage_xtile(Ag, k0, Abuf, t);       // A load+cvt overlaps B flight
        __syncthreads();
        mma_step(Abuf, Bbuf, wr, wc, c, g, acc);
        __syncthreads();                    // frees Abuf/Bbuf for epilogue
    }

    // ---- wave-private LDS retile (stride 68 ushorts) ----
    ushort* E = (ushort*)(smem + (size_t)w * 8704);
    const int n0w  = nblk*128 + wc*64;
    const int proj = n0w >> 9;
    const int h    = (n0w & 511) >> 6;
    const int m0w  = mblk*128 + wr*64;
    const int bi   = m0w >> 11;
    const int st0  = m0w & 2047;

    if (proj == 2) {
        #pragma unroll
        for (int mi = 0; mi < 4; ++mi)
            #pragma unroll
            for (int ni = 0; ni < 4; ++ni) {
                float bias = biasc[n0w + ni*16 + c];
                ushort4 pk = { f2bf(acc[mi][ni][0]+bias), f2bf(acc[mi][ni][1]+bias),
                               f2bf(acc[mi][ni][2]+bias), f2bf(acc[mi][ni][3]+bias) };
                *(ushort4*)&E[(ni*16 + c)*68 + mi*16 + g*4] = pk;
            }
    } else {
        #pragma unroll
        for (int mi = 0; mi < 4; ++mi)
            #pragma unroll
            for (int ni = 0; ni < 4; ++ni) {
                float bias = biasc[n0w + ni*16 + c];
                #pragma unroll
                for (int rg = 0; rg < 4; ++rg)
                    E[(mi*16 + g*4 + rg)*68 + ni*16 + c] = f2bf(acc[mi][ni][rg]+bias);
            }
    }

    const int l = lane;
    if (proj == 0) {
        char* base = (char*)Qb + ((size_t)(bi*HH + h)*64 + (st0 >> 5) + (l >> 5)) * 4096;
        #pragma unroll
        for (int j = 0; j < 8; ++j) {
            uint2 v0 = *(uint2*)&E[l*68 + j*8];
            uint2 v1 = *(uint2*)&E[l*68 + j*8 + 4];
            uint4 v = { v0.x, v0.y, v1.x, v1.y };
            *(uint4*)(base + j*512 + (l & 31)*16) = v;
        }
    } else if (proj == 1) {
        char* base = (char*)Kb + ((size_t)(bi*HH + h)*32 + (st0 >> 6)) * 8192;
        #pragma unroll
        for (int j = 0; j < 8; ++j) {
            uint2 v0 = *(uint2*)&E[l*68 + j*8];
            uint2 v1 = *(uint2*)&E[l*68 + j*8 + 4];
            uint4 v = { v0.x, v0.y, v1.x, v1.y };
            *(uint4*)(base + j*1024 + l*16) = v;
        }
    } else {
        char* base = (char*)Vtb + ((size_t)(bi*HH + h)*32 + (st0 >> 6)) * 8192;
        #pragma unroll
        for (int j = 0; j < 8; ++j) {
            uint2 v0 = *(uint2*)&E[l*68 + j*8];
            uint2 v1 = *(uint2*)&E[l*68 + j*8 + 4];
            uint4 v = { v0.x, v0.y, v1.x, v1.y };
            *(uint4*)(base + j*1024 + l*16) = v;
        }
    }
}

// ---------------------------------------------------------------------------
// Output projection GEMM + bias + residual -> bf16 ybuf via coalesced
// wave-LDS retile epilogue. grid (4, 64).
// ---------------------------------------------------------------------------
__global__ __launch_bounds__(256) void oproj_mm(
    const ushort* __restrict__ ctx, const ushort* __restrict__ wob,
    const float* __restrict__ bo, const float* __restrict__ resid,
    ushort* __restrict__ out)
{
    __shared__ char smem[34816];
    ushort* Abuf = (ushort*)smem;
    ushort* Bbuf = (ushort*)(smem + 16384);

    const int t = threadIdx.x, w = t >> 6, lane = t & 63;
    const int wr = w >> 1, wc = w & 1, c = lane & 15, g = lane >> 4;
    const int nblk = blockIdx.x, mblk = blockIdx.y;

    const ushort* Ag = ctx + (size_t)mblk * 128 * DD;
    const ushort* Bg = wob + (size_t)nblk * 128 * DD;

    f32x4 acc[4][4] = {};

    for (int k0 = 0; k0 < DD; k0 += 64) {
        stage_tile(Ag, k0, Abuf, t);
        stage_tile(Bg, k0, Bbuf, t);
        __syncthreads();
        mma_step(Abuf, Bbuf, wr, wc, c, g, acc);
        __syncthreads();
    }

    ushort* E = (ushort*)(smem + (size_t)w * 8704);
    const int n0w = nblk*128 + wc*64;
    const int m0w = mblk*128 + wr*64;

    #pragma unroll
    for (int mi = 0; mi < 4; ++mi)
        #pragma unroll
        for (int ni = 0; ni < 4; ++ni) {
            float bias = bo[n0w + ni*16 + c];
            #pragma unroll
            for (int rg = 0; rg < 4; ++rg) {
                int mm = m0w + mi*16 + g*4 + rg;
                float val = acc[mi][ni][rg] + bias
                          + resid[(size_t)mm*DD + n0w + ni*16 + c];
                E[(mi*16 + g*4 + rg)*68 + ni*16 + c] = f2bf(val);
            }
        }

    const int l = lane;
    #pragma unroll
    for (int j = 0; j < 8; ++j) {
        int row = j*8 + (l >> 3);
        uint2 v0 = *(uint2*)&E[row*68 + (l & 7)*8];
        uint2 v1 = *(uint2*)&E[row*68 + (l & 7)*8 + 4];
        uint4 v = { v0.x, v0.y, v1.x, v1.y };
        *(uint4*)&out[(size_t)(m0w + row)*DD + n0w + (l & 7)*8] = v;
    }
}

// ---------------------------------------------------------------------------
// Flash attention v10 (validated round 13): 32x32x16, in-register P, no-max
// exp2 softmax, kv-split 8 waves, pipelined PV, single ot accumulator.
// grid 512 x 512 thr.
// ---------------------------------------------------------------------------
__global__ __launch_bounds__(512, 4) void attn_kernel(
    const ushort* __restrict__ Q, const ushort* __restrict__ K,
    const ushort* __restrict__ Vt, ushort* __restrict__ ctx)
{
    __shared__ ushort Ks[2][2][64*64];    // [kvh][buf2] 32 KB
    __shared__ ushort Vts[2][3][64*64];   // [kvh][buf3] 48 KB

    const int t = threadIdx.x;
    const int w = t >> 6, l = t & 63;
    const int ln31 = l & 31, hi = l >> 5;
    const int qb = w & 3, kvh = w >> 2;

    const int id  = blockIdx.x;
    const int swz = (id & 7) * 64 + (id >> 3);
    const int qt = swz & 15;
    const int h  = (swz >> 4) & 7;
    const int b  = swz >> 7;
    const size_t bh = (size_t)b * HH + h;
    const int q0 = qt*128 + qb*32;

    const char* Qp = (const char*)Q + (bh*64 + (size_t)(qt*4 + qb)) * 4096;
    bf16x8 qf[4];
    #pragma unroll
    for (int s = 0; s < 4; ++s)
        qf[s] = *(const bf16x8*)(Qp + (2*s + hi)*512 + ln31*16);

    const int t2 = t & 255;
    const int NT = 16;
    const size_t kvbase = bh * 32;

#define ATTN_STAGE(kvi, kb_, vb_) do {                                      \
        const size_t tb_ = (kvbase + (size_t)(kvh*NT + (kvi))) * 8192;      \
        const char* kp_ = (const char*)K  + tb_;                            \
        const char* vp_ = (const char*)Vt + tb_;                            \
        gload16(kp_ + t2*16,        (char*)&Ks[kvh][kb_][0] + t2*16);       \
        gload16(kp_ + 4096 + t2*16, (char*)&Ks[kvh][kb_][0] + 4096 + t2*16);\
        gload16(vp_ + t2*16,        (char*)&Vts[kvh][vb_][0] + t2*16);      \
        gload16(vp_ + 4096 + t2*16, (char*)&Vts[kvh][vb_][0] + 4096 + t2*16);\
    } while (0)

#define QKT(kb_, ST) do {                                                   \
        const char* Kc_ = (const char*)&Ks[kvh][kb_][0];                    \
        __builtin_amdgcn_s_setprio(1);                                      \
        _Pragma("unroll")                                                   \
        for (int kt = 0; kt < 2; ++kt) {                                    \
            f32x16 z_ = {};                                                 \
            _Pragma("unroll")                                               \
            for (int s = 0; s < 4; ++s) {                                   \
                bf16x8 kf_ = *(const bf16x8*)(Kc_ + ((2*s + hi) << 10)      \
                                                  + ((kt*32 + ln31) << 4)); \
                z_ = __builtin_amdgcn_mfma_f32_32x32x16_bf16(kf_, qf[s], z_, 0, 0, 0); \
            }                                                               \
            ST[kt] = z_;                                                    \
        }                                                                   \
        __builtin_amdgcn_s_setprio(0);                                      \
    } while (0)

#define PVSTEP(vb_, PB) do {                                                \
        const char* Vc_ = (const char*)&Vts[kvh][vb_][0];                   \
        __builtin_amdgcn_s_setprio(1);                                      \
        _Pragma("unroll")                                                   \
        for (int kt = 0; kt < 2; ++kt)                                      \
            _Pragma("unroll")                                               \
            for (int s2 = 0; s2 < 2; ++s2)                                  \
                _Pragma("unroll")                                           \
                for (int dt = 0; dt < 2; ++dt) {                            \
                    bf16x8 vf_ = *(const bf16x8*)(Vc_ + ((kt*4 + 2*s2 + hi) << 10) \
                                                      + ((dt*32 + ln31) << 4));    \
                    ot[dt] = __builtin_amdgcn_mfma_f32_32x32x16_bf16(vf_, PB[kt][s2], ot[dt], 0, 0, 0); \
                }                                                           \
        __builtin_amdgcn_s_setprio(0);                                      \
    } while (0)

#define SOFTPACK(ST, PB) do {                                               \
        _Pragma("unroll")                                                   \
        for (int kt = 0; kt < 2; ++kt)                                      \
            _Pragma("unroll")                                               \
            for (int i = 0; i < 16; ++i)                                    \
                ST[kt][i] = exp2_hw(ST[kt][i]);                             \
        {                                                                   \
            float ps_[16];                                                  \
            _Pragma("unroll")                                               \
            for (int i = 0; i < 16; ++i) ps_[i] = ST[0][i] + ST[1][i];      \
            _Pragma("unroll")                                               \
            for (int i = 0; i < 8; ++i)  ps_[i] += ps_[i+8];                \
            _Pragma("unroll")                                               \
            for (int i = 0; i < 4; ++i)  ps_[i] += ps_[i+4];                \
            float psum_ = (ps_[0] + ps_[1]) + (ps_[2] + ps_[3]);            \
            float pa_ = psum_, pb2_ = psum_;                                \
            plane_swapf(pa_, pb2_);                                         \
            lsum += pa_ + pb2_;                                             \
        }                                                                   \
        unsigned dk_[2][4][2];                                              \
        _Pragma("unroll")                                                   \
        for (int kt = 0; kt < 2; ++kt)                                      \
            _Pragma("unroll")                                               \
            for (int rb = 0; rb < 4; ++rb) {                                \
                dk_[kt][rb][0] = cvt_pk_bf16(ST[kt][4*rb+0], ST[kt][4*rb+1]);\
                dk_[kt][rb][1] = cvt_pk_bf16(ST[kt][4*rb+2], ST[kt][4*rb+3]);\
            }                                                               \
        _Pragma("unroll")                                                   \
        for (int kt = 0; kt < 2; ++kt)                                      \
            _Pragma("unroll")                                               \
            for (int s2 = 0; s2 < 2; ++s2) {                                \
                unsigned a0_ = dk_[kt][2*s2][0], b0_ = dk_[kt][2*s2+1][0];  \
                unsigned a1_ = dk_[kt][2*s2][1], b1_ = dk_[kt][2*s2+1][1];  \
                plane_swap(a0_, b0_);                                       \
                plane_swap(a1_, b1_);                                       \
                PB[kt][s2] = pack4(a0_, a1_, b0_, b1_);                     \
            }                                                               \
    } while (0)

#define ITER(kv, PBP, PBC) do {                                             \
        __syncthreads();                                                    \
        if ((kv) + 1 < NT) ATTN_STAGE((kv)+1, ((kv)+1)&1, ((kv)+1)%3);      \
        f32x16 stl[2];                                                      \
        QKT((kv)&1, stl);                                                   \
        PVSTEP(((kv)-1)%3, PBP);                                            \
        SOFTPACK(stl, PBC);                                                 \
    } while (0)

    f32x16 ot[2] = {};
    float lsum = 0.f;
    bf16x8 pbA[2][2], pbB[2][2];

    // prologue: peel kv = 0 (no PV yet)
    ATTN_STAGE(0, 0, 0);
    __syncthreads();
    ATTN_STAGE(1, 1, 1);
    {
        f32x16 stl[2];
        QKT(0, stl);
        SOFTPACK(stl, pbA);
    }

    for (int kv = 1; kv <= 13; kv += 2) {
        ITER(kv,     pbA, pbB);
        ITER(kv + 1, pbB, pbA);
    }
    ITER(15, pbA, pbB);
    PVSTEP(15 % 3, pbB);                   // drain last PV

#undef ITER
#undef SOFTPACK
#undef PVSTEP
#undef QKT
#undef ATTN_STAGE

    // ---- intra-block combine of the two kv-halves (additive partials) ----
    __syncthreads();
    float* comb = (float*)&Vts[0][0][0];   // 33792 B needed <= 48 KB
    float* p = comb + (size_t)(qb*64 + l) * 33;
    if (kvh == 0) {
        #pragma unroll
        for (int i = 0; i < 16; ++i) { p[i] = ot[0][i]; p[16+i] = ot[1][i]; }
        p[32] = lsum;
    }
    __syncthreads();
    if (kvh == 1) {
        const float rl = 1.f / (lsum + p[32]);
        ushort* outp = ctx + ((size_t)b*SS + q0 + ln31) * DD + h*DHH;
        #pragma unroll
        for (int dt = 0; dt < 2; ++dt)
            #pragma unroll
            for (int rb = 0; rb < 4; ++rb) {
                ushort4 o = { f2bf((ot[dt][4*rb+0] + p[dt*16+4*rb+0])*rl),
                              f2bf((ot[dt][4*rb+1] + p[dt*16+4*rb+1])*rl),
                              f2bf((ot[dt][4*rb+2] + p[dt*16+4*rb+2])*rl),
                              f2bf((ot[dt][4*rb+3] + p[dt*16+4*rb+3])*rl) };
                *(ushort4*)&outp[dt*32 + rb*8 + hi*4] = o;
            }
    }
}

// ---------------------------------------------------------------------------
// Row LayerNorm (bf16 input, f32 output)
// ---------------------------------------------------------------------------
__global__ __launch_bounds__(256) void ln_kernel(
    const ushort* __restrict__ y, const float* __restrict__ gamma,
    const float* __restrict__ beta, float* __restrict__ out)
{
    const int row = blockIdx.x;
    const int t = threadIdx.x;

    unsigned u = *(const unsigned*)&y[(size_t)row * DD + t*2];
    union { unsigned u; float f; } lo, hi;
    lo.u = (u & 0xFFFFu) << 16;
    hi.u = u & 0xFFFF0000u;
    float2 v = { lo.f, hi.f };

    float s  = v.x + v.y;
    float sq = v.x*v.x + v.y*v.y;
    #pragma unroll
    for (int off = 1; off < 64; off <<= 1) {
        s  += __shfl_xor(s,  off);
        sq += __shfl_xor(sq, off);
    }
    __shared__ float ss[4], ssq[4];
    int wv = t >> 6;
    if ((t & 63) == 0) { ss[wv] = s; ssq[wv] = sq; }
    __syncthreads();
    s  = ss[0] + ss[1] + ss[2] + ss[3];
    sq = ssq[0] + ssq[1] + ssq[2] + ssq[3];

    float mean = s * (1.0f / DD);
    float var  = sq * (1.0f / DD) - mean * mean;
    float rstd = rsqrtf(var + LN_EPS);

    float2 g  = *(const float2*)&gamma[t*2];
    float2 be = *(const float2*)&beta[t*2];
    float2 o;
    o.x = (v.x - mean) * rstd * g.x + be.x;
    o.y = (v.y - mean) * rstd * g.y + be.y;
    *(float2*)&out[(size_t)row * DD + t*2] = o;
}

// ---------------------------------------------------------------------------
extern "C" void kernel_launch(void* const* d_in, const int* in_sizes, int n_in,
                              void* d_out, int out_size, void* d_ws, size_t ws_size,
                              hipStream_t stream)
{
    const float* x     = (const float*)d_in[0];
    const float* wq    = (const float*)d_in[1];
    const float* bq    = (const float*)d_in[2];
    const float* wk    = (const float*)d_in[3];
    const float* bk    = (const float*)d_in[4];
    const float* wv    = (const float*)d_in[5];
    const float* bv    = (const float*)d_in[6];
    const float* wo    = (const float*)d_in[7];
    const float* bo    = (const float*)d_in[8];
    const float* gamma = (const float*)d_in[9];
    const float* beta  = (const float*)d_in[10];

    char* wsb = (char*)d_ws;
    const size_t MB = 1u << 20;
    ushort* ybuf  = (ushort*)(wsb + 0*MB);    // 8 MB bf16
    ushort* wb    = (ushort*)(wsb + 8*MB);    // 2 MB
    float*  biasc = (float* )(wsb + 10*MB);   // 6 KB
    ushort* Qb    = (ushort*)(wsb + 11*MB);   // fragment-major
    ushort* Kb    = (ushort*)(wsb + 19*MB);   // fragment-major
    ushort* Vtb   = (ushort*)(wsb + 27*MB);   // fragment-major transposed
    ushort* ctxb  = (ushort*)(wsb + 35*MB);

    wcast_kernel<<<512, 256, 0, stream>>>(wq, wk, wv, wo, bq, bk, bv, wb, biasc);
    {
        qkv_mm<<<768, 256, 0, stream>>>(x, wb, biasc, Qb, Kb, Vtb);
    }
    {
        attn_kernel<<<512, 512, 0, stream>>>(Qb, Kb, Vtb, ctxb);
    }
    {
        dim3 grid(4, 64);
        oproj_mm<<<grid, 256, 0, stream>>>(ctxb, wb + 3*DD*DD, bo, x, ybuf);
    }
    ln_kernel<<<MROWS, 256, 0, stream>>>(ybuf, gamma, beta, (float*)d_out);
}

// Round 15
// 96.350 us; speedup vs baseline: 2.0524x; 1.0600x over previous
//
#include <hip/hip_runtime.h>
#include <hip/hip_bf16.h>
#include <math.h>

#define BB 4
#define SS 2048
#define DD 512
#define HH 8
#define DHH 64
#define MROWS (BB*SS)

constexpr float SCALE  = 0.044194173824159216f;            // 1/sqrt(512)
constexpr float QSCALE = (float)(0.044194173824159216 * 1.4426950408889634); // SCALE*log2(e)
constexpr float LN_EPS = 1e-5f;

typedef __attribute__((ext_vector_type(8)))  short bf16x8;
typedef __attribute__((ext_vector_type(4)))  float f32x4;
typedef __attribute__((ext_vector_type(16))) float f32x16;

__device__ __forceinline__ ushort f2bf(float f) {
    __hip_bfloat16 h = __float2bfloat16(f);
    ushort u; __builtin_memcpy(&u, &h, 2);
    return u;
}

__device__ __forceinline__ float exp2_hw(float x) {
#if __has_builtin(__builtin_amdgcn_exp2f)
    return __builtin_amdgcn_exp2f(x);
#else
    return exp2f(x);
#endif
}

__device__ __forceinline__ unsigned cvt_pk_bf16(float lo, float hi) {
    unsigned r;
    asm("v_cvt_pk_bf16_f32 %0, %1, %2" : "=v"(r) : "v"(lo), "v"(hi));
    return r;
}
__device__ __forceinline__ void plane_swap(unsigned &a, unsigned &b) {
    asm("v_permlane32_swap_b32 %0, %1" : "+v"(a), "+v"(b));
}
__device__ __forceinline__ void plane_swapf(float &a, float &b) {
    asm("v_permlane32_swap_b32 %0, %1" : "+v"(a), "+v"(b));
}
__device__ __forceinline__ bf16x8 pack4(unsigned a0, unsigned a1, unsigned b0, unsigned b1) {
    union { unsigned u[4]; bf16x8 v; } x;
    x.u[0] = a0; x.u[1] = a1; x.u[2] = b0; x.u[3] = b1;
    return x.v;
}

__device__ __forceinline__ void gload16(const void* gsrc, void* lds_dst) {
    __builtin_amdgcn_global_load_lds(
        (const __attribute__((address_space(1))) unsigned int*)gsrc,
        (__attribute__((address_space(3))) unsigned int*)lds_dst,
        16, 0, 0);
}

// ---------------------------------------------------------------------------
// Cast/pack: xb = bf16(x); wb = bf16([wq*QS; wk; wv; wo]); biasc = [bq*QS,bk,bv]
// grid 2048, block 256  (round-11 validated; ~BW-bound)
// ---------------------------------------------------------------------------
__global__ __launch_bounds__(256) void cast_kernel(
    const float* __restrict__ x,
    const float* __restrict__ wq, const float* __restrict__ wk,
    const float* __restrict__ wv, const float* __restrict__ wo,
    const float* __restrict__ bq, const float* __restrict__ bk,
    const float* __restrict__ bv,
    ushort* __restrict__ xb, ushort* __restrict__ wb, float* __restrict__ biasc)
{
    const int gid = blockIdx.x * 256 + threadIdx.x;
    if (gid < 1536) {
        float v = gid < 512 ? bq[gid] * QSCALE
                : gid < 1024 ? bk[gid - 512] : bv[gid - 1024];
        biasc[gid] = v;
    }
    const int NX4 = (MROWS * DD) / 4;     // 1048576
    const int NW4 = (DD * DD) / 4;        // 65536
    const int total = NX4 + 4 * NW4;      // 1310720
    for (int i = gid; i < total; i += gridDim.x * 256) {
        float4 v; ushort4 o;
        if (i < NX4) {
            v = ((const float4*)x)[i];
            o.x = f2bf(v.x); o.y = f2bf(v.y); o.z = f2bf(v.z); o.w = f2bf(v.w);
            ((ushort4*)xb)[i] = o;
        } else {
            int j = i - NX4;
            int which = j >> 16;
            int off = j & 65535;
            const float4* src = which == 0 ? (const float4*)wq
                              : which == 1 ? (const float4*)wk
                              : which == 2 ? (const float4*)wv : (const float4*)wo;
            v = src[off];
            float scl = which == 0 ? QSCALE : 1.0f;
            o.x = f2bf(v.x * scl); o.y = f2bf(v.y * scl);
            o.z = f2bf(v.z * scl); o.w = f2bf(v.w * scl);
            ((ushort4*)wb)[j] = o;
        }
    }
}

// ---------------------------------------------------------------------------
// Shared GEMM-BT machinery (validated rounds 2-14)
// ---------------------------------------------------------------------------
__device__ __forceinline__ void stage_tile(const ushort* __restrict__ g, int k0,
                                           ushort* lbuf, int t)
{
    #pragma unroll
    for (int i = 0; i < 4; ++i) {
        int cc = i * 256 + t;
        int row = cc >> 3, slot = cc & 7;
        gload16(g + row * DD + k0 + ((slot ^ (row & 7)) << 3), lbuf + cc * 8);
    }
}

__device__ __forceinline__ void mma_step(const ushort* Abuf, const ushort* Bbuf,
                                         int wr, int wc, int c, int g,
                                         f32x4 (&acc)[4][4])
{
    bf16x8 af[2][4], bf[2][4];
    #pragma unroll
    for (int kc = 0; kc < 2; ++kc) {
        int sw = ((kc * 4 + g) ^ (c & 7)) << 4;
        #pragma unroll
        for (int mi = 0; mi < 4; ++mi)
            af[kc][mi] = *(const bf16x8*)((const char*)Abuf + (wr*64 + mi*16 + c)*128 + sw);
        #pragma unroll
        for (int ni = 0; ni < 4; ++ni)
            bf[kc][ni] = *(const bf16x8*)((const char*)Bbuf + (wc*64 + ni*16 + c)*128 + sw);
    }
    __builtin_amdgcn_s_setprio(1);
    #pragma unroll
    for (int kc = 0; kc < 2; ++kc)
        #pragma unroll
        for (int mi = 0; mi < 4; ++mi)
            #pragma unroll
            for (int ni = 0; ni < 4; ++ni)
                acc[mi][ni] = __builtin_amdgcn_mfma_f32_16x16x32_bf16(
                    af[kc][mi], bf[kc][ni], acc[mi][ni], 0, 0, 0);
    __builtin_amdgcn_s_setprio(0);
}

// ---------------------------------------------------------------------------
// QKV projection GEMM. 1D grid 768, XCD-contiguous mapping (XCD i gets 96
// consecutive ids = 8 m-panels x 12 n-blocks -> x panels L2-resident).
// A staged async from bf16 xb (global_load_lds -- the round-11 proven path;
// the inline-f32 reg-staged variant measured 43-46us vs ~25us for this).
// Coalesced fragment-major epilogue.
//  Q: [bh][q/32][d/8][q%32][8]   K: [bh][s/64][d/8][s%64][8]
//  V: [bh][s/64][(s%64)/8][d][8] (transposed)
// ---------------------------------------------------------------------------
__global__ __launch_bounds__(256) void qkv_mm(
    const ushort* __restrict__ xb, const ushort* __restrict__ wb,
    const float* __restrict__ biasc,
    ushort* __restrict__ Qb, ushort* __restrict__ Kb, ushort* __restrict__ Vtb)
{
    __shared__ char smem[34816];            // Abuf16K + Bbuf16K; epi 4x8704
    ushort* Abuf = (ushort*)smem;
    ushort* Bbuf = (ushort*)(smem + 16384);

    const int t = threadIdx.x, w = t >> 6, lane = t & 63;
    const int wr = w >> 1, wc = w & 1, c = lane & 15, g = lane >> 4;

    const int id   = blockIdx.x;
    const int swz  = (id & 7) * 96 + (id >> 3);
    const int mblk = swz / 12;
    const int nblk = swz % 12;

    const ushort* Ag = xb + (size_t)mblk * 128 * DD;
    const ushort* Bg = wb + (size_t)nblk * 128 * DD;

    f32x4 acc[4][4] = {};

    for (int k0 = 0; k0 < DD; k0 += 64) {
        stage_tile(Ag, k0, Abuf, t);
        stage_tile(Bg, k0, Bbuf, t);
        __syncthreads();
        mma_step(Abuf, Bbuf, wr, wc, c, g, acc);
        __syncthreads();                    // frees Abuf/Bbuf for epilogue
    }

    // ---- wave-private LDS retile (stride 68 ushorts) ----
    ushort* E = (ushort*)(smem + (size_t)w * 8704);
    const int n0w  = nblk*128 + wc*64;
    const int proj = n0w >> 9;
    const int h    = (n0w & 511) >> 6;
    const int m0w  = mblk*128 + wr*64;
    const int bi   = m0w >> 11;
    const int st0  = m0w & 2047;

    if (proj == 2) {
        #pragma unroll
        for (int mi = 0; mi < 4; ++mi)
            #pragma unroll
            for (int ni = 0; ni < 4; ++ni) {
                float bias = biasc[n0w + ni*16 + c];
                ushort4 pk = { f2bf(acc[mi][ni][0]+bias), f2bf(acc[mi][ni][1]+bias),
                               f2bf(acc[mi][ni][2]+bias), f2bf(acc[mi][ni][3]+bias) };
                *(ushort4*)&E[(ni*16 + c)*68 + mi*16 + g*4] = pk;
            }
    } else {
        #pragma unroll
        for (int mi = 0; mi < 4; ++mi)
            #pragma unroll
            for (int ni = 0; ni < 4; ++ni) {
                float bias = biasc[n0w + ni*16 + c];
                #pragma unroll
                for (int rg = 0; rg < 4; ++rg)
                    E[(mi*16 + g*4 + rg)*68 + ni*16 + c] = f2bf(acc[mi][ni][rg]+bias);
            }
    }

    const int l = lane;
    if (proj == 0) {
        char* base = (char*)Qb + ((size_t)(bi*HH + h)*64 + (st0 >> 5) + (l >> 5)) * 4096;
        #pragma unroll
        for (int j = 0; j < 8; ++j) {
            uint2 v0 = *(uint2*)&E[l*68 + j*8];
            uint2 v1 = *(uint2*)&E[l*68 + j*8 + 4];
            uint4 v = { v0.x, v0.y, v1.x, v1.y };
            *(uint4*)(base + j*512 + (l & 31)*16) = v;
        }
    } else if (proj == 1) {
        char* base = (char*)Kb + ((size_t)(bi*HH + h)*32 + (st0 >> 6)) * 8192;
        #pragma unroll
        for (int j = 0; j < 8; ++j) {
            uint2 v0 = *(uint2*)&E[l*68 + j*8];
            uint2 v1 = *(uint2*)&E[l*68 + j*8 + 4];
            uint4 v = { v0.x, v0.y, v1.x, v1.y };
            *(uint4*)(base + j*1024 + l*16) = v;
        }
    } else {
        char* base = (char*)Vtb + ((size_t)(bi*HH + h)*32 + (st0 >> 6)) * 8192;
        #pragma unroll
        for (int j = 0; j < 8; ++j) {
            uint2 v0 = *(uint2*)&E[l*68 + j*8];
            uint2 v1 = *(uint2*)&E[l*68 + j*8 + 4];
            uint4 v = { v0.x, v0.y, v1.x, v1.y };
            *(uint4*)(base + j*1024 + l*16) = v;
        }
    }
}

// ---------------------------------------------------------------------------
// Output projection GEMM + bias + residual -> bf16 ybuf via coalesced
// wave-LDS retile epilogue. 1D grid 256, XCD-contiguous (8 m-panels x 4
// n-blocks per XCD -> ctx/wo L2-resident).
// ---------------------------------------------------------------------------
__global__ __launch_bounds__(256) void oproj_mm(
    const ushort* __restrict__ ctx, const ushort* __restrict__ wob,
    const float* __restrict__ bo, const float* __restrict__ resid,
    ushort* __restrict__ out)
{
    __shared__ char smem[34816];
    ushort* Abuf = (ushort*)smem;
    ushort* Bbuf = (ushort*)(smem + 16384);

    const int t = threadIdx.x, w = t >> 6, lane = t & 63;
    const int wr = w >> 1, wc = w & 1, c = lane & 15, g = lane >> 4;

    const int id   = blockIdx.x;
    const int swz  = (id & 7) * 32 + (id >> 3);
    const int mblk = swz >> 2;
    const int nblk = swz & 3;

    const ushort* Ag = ctx + (size_t)mblk * 128 * DD;
    const ushort* Bg = wob + (size_t)nblk * 128 * DD;

    f32x4 acc[4][4] = {};

    for (int k0 = 0; k0 < DD; k0 += 64) {
        stage_tile(Ag, k0, Abuf, t);
        stage_tile(Bg, k0, Bbuf, t);
        __syncthreads();
        mma_step(Abuf, Bbuf, wr, wc, c, g, acc);
        __syncthreads();
    }

    ushort* E = (ushort*)(smem + (size_t)w * 8704);
    const int n0w = nblk*128 + wc*64;
    const int m0w = mblk*128 + wr*64;

    #pragma unroll
    for (int mi = 0; mi < 4; ++mi)
        #pragma unroll
        for (int ni = 0; ni < 4; ++ni) {
            float bias = bo[n0w + ni*16 + c];
            #pragma unroll
            for (int rg = 0; rg < 4; ++rg) {
                int mm = m0w + mi*16 + g*4 + rg;
                float val = acc[mi][ni][rg] + bias
                          + resid[(size_t)mm*DD + n0w + ni*16 + c];
                E[(mi*16 + g*4 + rg)*68 + ni*16 + c] = f2bf(val);
            }
        }

    const int l = lane;
    #pragma unroll
    for (int j = 0; j < 8; ++j) {
        int row = j*8 + (l >> 3);
        uint2 v0 = *(uint2*)&E[row*68 + (l & 7)*8];
        uint2 v1 = *(uint2*)&E[row*68 + (l & 7)*8 + 4];
        uint4 v = { v0.x, v0.y, v1.x, v1.y };
        *(uint4*)&out[(size_t)(m0w + row)*DD + n0w + (l & 7)*8] = v;
    }
}

// ---------------------------------------------------------------------------
// Flash attention v10 (validated rounds 13-14): 32x32x16, in-register P,
// no-max exp2 softmax, kv-split 8 waves, pipelined PV, single ot accumulator.
// grid 512 x 512 thr.
// ---------------------------------------------------------------------------
__global__ __launch_bounds__(512, 4) void attn_kernel(
    const ushort* __restrict__ Q, const ushort* __restrict__ K,
    const ushort* __restrict__ Vt, ushort* __restrict__ ctx)
{
    __shared__ ushort Ks[2][2][64*64];    // [kvh][buf2] 32 KB
    __shared__ ushort Vts[2][3][64*64];   // [kvh][buf3] 48 KB

    const int t = threadIdx.x;
    const int w = t >> 6, l = t & 63;
    const int ln31 = l & 31, hi = l >> 5;
    const int qb = w & 3, kvh = w >> 2;

    const int id  = blockIdx.x;
    const int swz = (id & 7) * 64 + (id >> 3);
    const int qt = swz & 15;
    const int h  = (swz >> 4) & 7;
    const int b  = swz >> 7;
    const size_t bh = (size_t)b * HH + h;
    const int q0 = qt*128 + qb*32;

    const char* Qp = (const char*)Q + (bh*64 + (size_t)(qt*4 + qb)) * 4096;
    bf16x8 qf[4];
    #pragma unroll
    for (int s = 0; s < 4; ++s)
        qf[s] = *(const bf16x8*)(Qp + (2*s + hi)*512 + ln31*16);

    const int t2 = t & 255;
    const int NT = 16;
    const size_t kvbase = bh * 32;

#define ATTN_STAGE(kvi, kb_, vb_) do {                                      \
        const size_t tb_ = (kvbase + (size_t)(kvh*NT + (kvi))) * 8192;      \
        const char* kp_ = (const char*)K  + tb_;                            \
        const char* vp_ = (const char*)Vt + tb_;                            \
        gload16(kp_ + t2*16,        (char*)&Ks[kvh][kb_][0] + t2*16);       \
        gload16(kp_ + 4096 + t2*16, (char*)&Ks[kvh][kb_][0] + 4096 + t2*16);\
        gload16(vp_ + t2*16,        (char*)&Vts[kvh][vb_][0] + t2*16);      \
        gload16(vp_ + 4096 + t2*16, (char*)&Vts[kvh][vb_][0] + 4096 + t2*16);\
    } while (0)

#define QKT(kb_, ST) do {                                                   \
        const char* Kc_ = (const char*)&Ks[kvh][kb_][0];                    \
        __builtin_amdgcn_s_setprio(1);                                      \
        _Pragma("unroll")                                                   \
        for (int kt = 0; kt < 2; ++kt) {                                    \
            f32x16 z_ = {};                                                 \
            _Pragma("unroll")                                               \
            for (int s = 0; s < 4; ++s) {                                   \
                bf16x8 kf_ = *(const bf16x8*)(Kc_ + ((2*s + hi) << 10)      \
                                                  + ((kt*32 + ln31) << 4)); \
                z_ = __builtin_amdgcn_mfma_f32_32x32x16_bf16(kf_, qf[s], z_, 0, 0, 0); \
            }                                                               \
            ST[kt] = z_;                                                    \
        }                                                                   \
        __builtin_amdgcn_s_setprio(0);                                      \
    } while (0)

#define PVSTEP(vb_, PB) do {                                                \
        const char* Vc_ = (const char*)&Vts[kvh][vb_][0];                   \
        __builtin_amdgcn_s_setprio(1);                                      \
        _Pragma("unroll")                                                   \
        for (int kt = 0; kt < 2; ++kt)                                      \
            _Pragma("unroll")                                               \
            for (int s2 = 0; s2 < 2; ++s2)                                  \
                _Pragma("unroll")                                           \
                for (int dt = 0; dt < 2; ++dt) {                            \
                    bf16x8 vf_ = *(const bf16x8*)(Vc_ + ((kt*4 + 2*s2 + hi) << 10) \
                                                      + ((dt*32 + ln31) << 4));    \
                    ot[dt] = __builtin_amdgcn_mfma_f32_32x32x16_bf16(vf_, PB[kt][s2], ot[dt], 0, 0, 0); \
                }                                                           \
        __builtin_amdgcn_s_setprio(0);                                      \
    } while (0)

#define SOFTPACK(ST, PB) do {                                               \
        _Pragma("unroll")                                                   \
        for (int kt = 0; kt < 2; ++kt)                                      \
            _Pragma("unroll")                                               \
            for (int i = 0; i < 16; ++i)                                    \
                ST[kt][i] = exp2_hw(ST[kt][i]);                             \
        {                                                                   \
            float ps_[16];                                                  \
            _Pragma("unroll")                                               \
            for (int i = 0; i < 16; ++i) ps_[i] = ST[0][i] + ST[1][i];      \
            _Pragma("unroll")                                               \
            for (int i = 0; i < 8; ++i)  ps_[i] += ps_[i+8];                \
            _Pragma("unroll")                                               \
            for (int i = 0; i < 4; ++i)  ps_[i] += ps_[i+4];                \
            float psum_ = (ps_[0] + ps_[1]) + (ps_[2] + ps_[3]);            \
            float pa_ = psum_, pb2_ = psum_;                                \
            plane_swapf(pa_, pb2_);                                         \
            lsum += pa_ + pb2_;                                             \
        }                                                                   \
        unsigned dk_[2][4][2];                                              \
        _Pragma("unroll")                                                   \
        for (int kt = 0; kt < 2; ++kt)                                      \
            _Pragma("unroll")                                               \
            for (int rb = 0; rb < 4; ++rb) {                                \
                dk_[kt][rb][0] = cvt_pk_bf16(ST[kt][4*rb+0], ST[kt][4*rb+1]);\
                dk_[kt][rb][1] = cvt_pk_bf16(ST[kt][4*rb+2], ST[kt][4*rb+3]);\
            }                                                               \
        _Pragma("unroll")                                                   \
        for (int kt = 0; kt < 2; ++kt)                                      \
            _Pragma("unroll")                                               \
            for (int s2 = 0; s2 < 2; ++s2) {                                \
                unsigned a0_ = dk_[kt][2*s2][0], b0_ = dk_[kt][2*s2+1][0];  \
                unsigned a1_ = dk_[kt][2*s2][1], b1_ = dk_[kt][2*s2+1][1];  \
                plane_swap(a0_, b0_);                                       \
                plane_swap(a1_, b1_);                                       \
                PB[kt][s2] = pack4(a0_, a1_, b0_, b1_);                     \
            }                                                               \
    } while (0)

#define ITER(kv, PBP, PBC) do {                                             \
        __syncthreads();                                                    \
        if ((kv) + 1 < NT) ATTN_STAGE((kv)+1, ((kv)+1)&1, ((kv)+1)%3);      \
        f32x16 stl[2];                                                      \
        QKT((kv)&1, stl);                                                   \
        PVSTEP(((kv)-1)%3, PBP);                                            \
        SOFTPACK(stl, PBC);                                                 \
    } while (0)

    f32x16 ot[2] = {};
    float lsum = 0.f;
    bf16x8 pbA[2][2], pbB[2][2];

    // prologue: peel kv = 0 (no PV yet)
    ATTN_STAGE(0, 0, 0);
    __syncthreads();
    ATTN_STAGE(1, 1, 1);
    {
        f32x16 stl[2];
        QKT(0, stl);
        SOFTPACK(stl, pbA);
    }

    for (int kv = 1; kv <= 13; kv += 2) {
        ITER(kv,     pbA, pbB);
        ITER(kv + 1, pbB, pbA);
    }
    ITER(15, pbA, pbB);
    PVSTEP(15 % 3, pbB);                   // drain last PV

#undef ITER
#undef SOFTPACK
#undef PVSTEP
#undef QKT
#undef ATTN_STAGE

    // ---- intra-block combine of the two kv-halves (additive partials) ----
    __syncthreads();
    float* comb = (float*)&Vts[0][0][0];   // 33792 B needed <= 48 KB
    float* p = comb + (size_t)(qb*64 + l) * 33;
    if (kvh == 0) {
        #pragma unroll
        for (int i = 0; i < 16; ++i) { p[i] = ot[0][i]; p[16+i] = ot[1][i]; }
        p[32] = lsum;
    }
    __syncthreads();
    if (kvh == 1) {
        const float rl = 1.f / (lsum + p[32]);
        ushort* outp = ctx + ((size_t)b*SS + q0 + ln31) * DD + h*DHH;
        #pragma unroll
        for (int dt = 0; dt < 2; ++dt)
            #pragma unroll
            for (int rb = 0; rb < 4; ++rb) {
                ushort4 o = { f2bf((ot[dt][4*rb+0] + p[dt*16+4*rb+0])*rl),
                              f2bf((ot[dt][4*rb+1] + p[dt*16+4*rb+1])*rl),
                              f2bf((ot[dt][4*rb+2] + p[dt*16+4*rb+2])*rl),
                              f2bf((ot[dt][4*rb+3] + p[dt*16+4*rb+3])*rl) };
                *(ushort4*)&outp[dt*32 + rb*8 + hi*4] = o;
            }
    }
}

// ---------------------------------------------------------------------------
// Row LayerNorm (bf16 input, f32 output)
// ---------------------------------------------------------------------------
__global__ __launch_bounds__(256) void ln_kernel(
    const ushort* __restrict__ y, const float* __restrict__ gamma,
    const float* __restrict__ beta, float* __restrict__ out)
{
    const int row = blockIdx.x;
    const int t = threadIdx.x;

    unsigned u = *(const unsigned*)&y[(size_t)row * DD + t*2];
    union { unsigned u; float f; } lo, hi;
    lo.u = (u & 0xFFFFu) << 16;
    hi.u = u & 0xFFFF0000u;
    float2 v = { lo.f, hi.f };

    float s  = v.x + v.y;
    float sq = v.x*v.x + v.y*v.y;
    #pragma unroll
    for (int off = 1; off < 64; off <<= 1) {
        s  += __shfl_xor(s,  off);
        sq += __shfl_xor(sq, off);
    }
    __shared__ float ss[4], ssq[4];
    int wv = t >> 6;
    if ((t & 63) == 0) { ss[wv] = s; ssq[wv] = sq; }
    __syncthreads();
    s  = ss[0] + ss[1] + ss[2] + ss[3];
    sq = ssq[0] + ssq[1] + ssq[2] + ssq[3];

    float mean = s * (1.0f / DD);
    float var  = sq * (1.0f / DD) - mean * mean;
    float rstd = rsqrtf(var + LN_EPS);

    float2 g  = *(const float2*)&gamma[t*2];
    float2 be = *(const float2*)&beta[t*2];
    float2 o;
    o.x = (v.x - mean) * rstd * g.x + be.x;
    o.y = (v.y - mean) * rstd * g.y + be.y;
    *(float2*)&out[(size_t)row * DD + t*2] = o;
}

// ---------------------------------------------------------------------------
extern "C" void kernel_launch(void* const* d_in, const int* in_sizes, int n_in,
                              void* d_out, int out_size, void* d_ws, size_t ws_size,
                              hipStream_t stream)
{
    const float* x     = (const float*)d_in[0];
    const float* wq    = (const float*)d_in[1];
    const float* bq    = (const float*)d_in[2];
    const float* wk    = (const float*)d_in[3];
    const float* bk    = (const float*)d_in[4];
    const float* wv    = (const float*)d_in[5];
    const float* bv    = (const float*)d_in[6];
    const float* wo    = (const float*)d_in[7];
    const float* bo    = (const float*)d_in[8];
    const float* gamma = (const float*)d_in[9];
    const float* beta  = (const float*)d_in[10];

    char* wsb = (char*)d_ws;
    const size_t MB = 1u << 20;
    ushort* xb    = (ushort*)(wsb + 0*MB);    // 8 MB; dead after qkv -> ybuf
    ushort* wb    = (ushort*)(wsb + 8*MB);    // 2 MB
    float*  biasc = (float* )(wsb + 10*MB);   // 6 KB
    ushort* Qb    = (ushort*)(wsb + 11*MB);   // fragment-major
    ushort* Kb    = (ushort*)(wsb + 19*MB);   // fragment-major
    ushort* Vtb   = (ushort*)(wsb + 27*MB);   // fragment-major transposed
    ushort* ctxb  = (ushort*)(wsb + 35*MB);
    ushort* ybuf  = xb;                        // alias (xb dead after qkv)

    cast_kernel<<<2048, 256, 0, stream>>>(x, wq, wk, wv, wo, bq, bk, bv,
                                          xb, wb, biasc);
    {
        qkv_mm<<<768, 256, 0, stream>>>(xb, wb, biasc, Qb, Kb, Vtb);
    }
    {
        attn_kernel<<<512, 512, 0, stream>>>(Qb, Kb, Vtb, ctxb);
    }
    {
        oproj_mm<<<256, 256, 0, stream>>>(ctxb, wb + 3*DD*DD, bo, x, ybuf);
    }
    ln_kernel<<<MROWS, 256, 0, stream>>>(ybuf, gamma, beta, (float*)d_out);
}

// Round 16
// 93.968 us; speedup vs baseline: 2.1045x; 1.0254x over previous
//
#include <hip/hip_runtime.h>
#include <hip/hip_bf16.h>
#include <math.h>

#define BB 4
#define SS 2048
#define DD 512
#define HH 8
#define DHH 64
#define MROWS (BB*SS)

constexpr float SCALE  = 0.044194173824159216f;            // 1/sqrt(512)
constexpr float QSCALE = (float)(0.044194173824159216 * 1.4426950408889634); // SCALE*log2(e)
constexpr float LN_EPS = 1e-5f;

typedef __attribute__((ext_vector_type(8)))  short bf16x8;
typedef __attribute__((ext_vector_type(4)))  float f32x4;
typedef __attribute__((ext_vector_type(16))) float f32x16;

__device__ __forceinline__ ushort f2bf(float f) {
    __hip_bfloat16 h = __float2bfloat16(f);
    ushort u; __builtin_memcpy(&u, &h, 2);
    return u;
}

__device__ __forceinline__ float exp2_hw(float x) {
#if __has_builtin(__builtin_amdgcn_exp2f)
    return __builtin_amdgcn_exp2f(x);
#else
    return exp2f(x);
#endif
}

__device__ __forceinline__ unsigned cvt_pk_bf16(float lo, float hi) {
    unsigned r;
    asm("v_cvt_pk_bf16_f32 %0, %1, %2" : "=v"(r) : "v"(lo), "v"(hi));
    return r;
}
__device__ __forceinline__ void plane_swap(unsigned &a, unsigned &b) {
    asm("v_permlane32_swap_b32 %0, %1" : "+v"(a), "+v"(b));
}
__device__ __forceinline__ void plane_swapf(float &a, float &b) {
    asm("v_permlane32_swap_b32 %0, %1" : "+v"(a), "+v"(b));
}
__device__ __forceinline__ bf16x8 pack4(unsigned a0, unsigned a1, unsigned b0, unsigned b1) {
    union { unsigned u[4]; bf16x8 v; } x;
    x.u[0] = a0; x.u[1] = a1; x.u[2] = b0; x.u[3] = b1;
    return x.v;
}

__device__ __forceinline__ void gload16(const void* gsrc, void* lds_dst) {
    __builtin_amdgcn_global_load_lds(
        (const __attribute__((address_space(1))) unsigned int*)gsrc,
        (__attribute__((address_space(3))) unsigned int*)lds_dst,
        16, 0, 0);
}

// ---------------------------------------------------------------------------
// Cast/pack: xb = bf16(x); wb = bf16([wq*QS; wk; wv; wo]); biasc = [bq*QS,bk,bv]
// grid 2048, block 256
// ---------------------------------------------------------------------------
__global__ __launch_bounds__(256) void cast_kernel(
    const float* __restrict__ x,
    const float* __restrict__ wq, const float* __restrict__ wk,
    const float* __restrict__ wv, const float* __restrict__ wo,
    const float* __restrict__ bq, const float* __restrict__ bk,
    const float* __restrict__ bv,
    ushort* __restrict__ xb, ushort* __restrict__ wb, float* __restrict__ biasc)
{
    const int gid = blockIdx.x * 256 + threadIdx.x;
    if (gid < 1536) {
        float v = gid < 512 ? bq[gid] * QSCALE
                : gid < 1024 ? bk[gid - 512] : bv[gid - 1024];
        biasc[gid] = v;
    }
    const int NX4 = (MROWS * DD) / 4;     // 1048576
    const int NW4 = (DD * DD) / 4;        // 65536
    const int total = NX4 + 4 * NW4;      // 1310720
    for (int i = gid; i < total; i += gridDim.x * 256) {
        float4 v; ushort4 o;
        if (i < NX4) {
            v = ((const float4*)x)[i];
            o.x = f2bf(v.x); o.y = f2bf(v.y); o.z = f2bf(v.z); o.w = f2bf(v.w);
            ((ushort4*)xb)[i] = o;
        } else {
            int j = i - NX4;
            int which = j >> 16;
            int off = j & 65535;
            const float4* src = which == 0 ? (const float4*)wq
                              : which == 1 ? (const float4*)wk
                              : which == 2 ? (const float4*)wv : (const float4*)wo;
            v = src[off];
            float scl = which == 0 ? QSCALE : 1.0f;
            o.x = f2bf(v.x * scl); o.y = f2bf(v.y * scl);
            o.z = f2bf(v.z * scl); o.w = f2bf(v.w * scl);
            ((ushort4*)wb)[j] = o;
        }
    }
}

// ---------------------------------------------------------------------------
// Shared GEMM-BT machinery (validated rounds 2-15)
// ---------------------------------------------------------------------------
__device__ __forceinline__ void stage_tile(const ushort* __restrict__ g, int k0,
                                           ushort* lbuf, int t)
{
    #pragma unroll
    for (int i = 0; i < 4; ++i) {
        int cc = i * 256 + t;
        int row = cc >> 3, slot = cc & 7;
        gload16(g + row * DD + k0 + ((slot ^ (row & 7)) << 3), lbuf + cc * 8);
    }
}

__device__ __forceinline__ void mma_step(const ushort* Abuf, const ushort* Bbuf,
                                         int wr, int wc, int c, int g,
                                         f32x4 (&acc)[4][4])
{
    bf16x8 af[2][4], bf[2][4];
    #pragma unroll
    for (int kc = 0; kc < 2; ++kc) {
        int sw = ((kc * 4 + g) ^ (c & 7)) << 4;
        #pragma unroll
        for (int mi = 0; mi < 4; ++mi)
            af[kc][mi] = *(const bf16x8*)((const char*)Abuf + (wr*64 + mi*16 + c)*128 + sw);
        #pragma unroll
        for (int ni = 0; ni < 4; ++ni)
            bf[kc][ni] = *(const bf16x8*)((const char*)Bbuf + (wc*64 + ni*16 + c)*128 + sw);
    }
    __builtin_amdgcn_s_setprio(1);
    #pragma unroll
    for (int kc = 0; kc < 2; ++kc)
        #pragma unroll
        for (int mi = 0; mi < 4; ++mi)
            #pragma unroll
            for (int ni = 0; ni < 4; ++ni)
                acc[mi][ni] = __builtin_amdgcn_mfma_f32_16x16x32_bf16(
                    af[kc][mi], bf[kc][ni], acc[mi][ni], 0, 0, 0);
    __builtin_amdgcn_s_setprio(0);
}

// ---------------------------------------------------------------------------
// QKV projection GEMM. 1D grid 768, XCD-contiguous. bf16 A via global_load_lds.
// Coalesced fragment-major epilogue.
//  Q: [bh][q/32][d/8][q%32][8]   K: [bh][s/64][d/8][s%64][8]
//  V: [bh][s/64][(s%64)/8][d][8] (transposed)
// ---------------------------------------------------------------------------
__global__ __launch_bounds__(256) void qkv_mm(
    const ushort* __restrict__ xb, const ushort* __restrict__ wb,
    const float* __restrict__ biasc,
    ushort* __restrict__ Qb, ushort* __restrict__ Kb, ushort* __restrict__ Vtb)
{
    __shared__ char smem[34816];            // Abuf16K + Bbuf16K; epi 4x8704
    ushort* Abuf = (ushort*)smem;
    ushort* Bbuf = (ushort*)(smem + 16384);

    const int t = threadIdx.x, w = t >> 6, lane = t & 63;
    const int wr = w >> 1, wc = w & 1, c = lane & 15, g = lane >> 4;

    const int id   = blockIdx.x;
    const int swz  = (id & 7) * 96 + (id >> 3);
    const int mblk = swz / 12;
    const int nblk = swz % 12;

    const ushort* Ag = xb + (size_t)mblk * 128 * DD;
    const ushort* Bg = wb + (size_t)nblk * 128 * DD;

    f32x4 acc[4][4] = {};

    for (int k0 = 0; k0 < DD; k0 += 64) {
        stage_tile(Ag, k0, Abuf, t);
        stage_tile(Bg, k0, Bbuf, t);
        __syncthreads();
        mma_step(Abuf, Bbuf, wr, wc, c, g, acc);
        __syncthreads();                    // frees Abuf/Bbuf for epilogue
    }

    // ---- wave-private LDS retile (stride 68 ushorts) ----
    ushort* E = (ushort*)(smem + (size_t)w * 8704);
    const int n0w  = nblk*128 + wc*64;
    const int proj = n0w >> 9;
    const int h    = (n0w & 511) >> 6;
    const int m0w  = mblk*128 + wr*64;
    const int bi   = m0w >> 11;
    const int st0  = m0w & 2047;

    if (proj == 2) {
        #pragma unroll
        for (int mi = 0; mi < 4; ++mi)
            #pragma unroll
            for (int ni = 0; ni < 4; ++ni) {
                float bias = biasc[n0w + ni*16 + c];
                ushort4 pk = { f2bf(acc[mi][ni][0]+bias), f2bf(acc[mi][ni][1]+bias),
                               f2bf(acc[mi][ni][2]+bias), f2bf(acc[mi][ni][3]+bias) };
                *(ushort4*)&E[(ni*16 + c)*68 + mi*16 + g*4] = pk;
            }
    } else {
        #pragma unroll
        for (int mi = 0; mi < 4; ++mi)
            #pragma unroll
            for (int ni = 0; ni < 4; ++ni) {
                float bias = biasc[n0w + ni*16 + c];
                #pragma unroll
                for (int rg = 0; rg < 4; ++rg)
                    E[(mi*16 + g*4 + rg)*68 + ni*16 + c] = f2bf(acc[mi][ni][rg]+bias);
            }
    }

    const int l = lane;
    if (proj == 0) {
        char* base = (char*)Qb + ((size_t)(bi*HH + h)*64 + (st0 >> 5) + (l >> 5)) * 4096;
        #pragma unroll
        for (int j = 0; j < 8; ++j) {
            uint2 v0 = *(uint2*)&E[l*68 + j*8];
            uint2 v1 = *(uint2*)&E[l*68 + j*8 + 4];
            uint4 v = { v0.x, v0.y, v1.x, v1.y };
            *(uint4*)(base + j*512 + (l & 31)*16) = v;
        }
    } else if (proj == 1) {
        char* base = (char*)Kb + ((size_t)(bi*HH + h)*32 + (st0 >> 6)) * 8192;
        #pragma unroll
        for (int j = 0; j < 8; ++j) {
            uint2 v0 = *(uint2*)&E[l*68 + j*8];
            uint2 v1 = *(uint2*)&E[l*68 + j*8 + 4];
            uint4 v = { v0.x, v0.y, v1.x, v1.y };
            *(uint4*)(base + j*1024 + l*16) = v;
        }
    } else {
        char* base = (char*)Vtb + ((size_t)(bi*HH + h)*32 + (st0 >> 6)) * 8192;
        #pragma unroll
        for (int j = 0; j < 8; ++j) {
            uint2 v0 = *(uint2*)&E[l*68 + j*8];
            uint2 v1 = *(uint2*)&E[l*68 + j*8 + 4];
            uint4 v = { v0.x, v0.y, v1.x, v1.y };
            *(uint4*)(base + j*1024 + l*16) = v;
        }
    }
}

// ---------------------------------------------------------------------------
// Output projection GEMM + bias + residual -> bf16 ybuf. 1D grid 256,
// XCD-contiguous.
// ---------------------------------------------------------------------------
__global__ __launch_bounds__(256) void oproj_mm(
    const ushort* __restrict__ ctx, const ushort* __restrict__ wob,
    const float* __restrict__ bo, const float* __restrict__ resid,
    ushort* __restrict__ out)
{
    __shared__ char smem[34816];
    ushort* Abuf = (ushort*)smem;
    ushort* Bbuf = (ushort*)(smem + 16384);

    const int t = threadIdx.x, w = t >> 6, lane = t & 63;
    const int wr = w >> 1, wc = w & 1, c = lane & 15, g = lane >> 4;

    const int id   = blockIdx.x;
    const int swz  = (id & 7) * 32 + (id >> 3);
    const int mblk = swz >> 2;
    const int nblk = swz & 3;

    const ushort* Ag = ctx + (size_t)mblk * 128 * DD;
    const ushort* Bg = wob + (size_t)nblk * 128 * DD;

    f32x4 acc[4][4] = {};

    for (int k0 = 0; k0 < DD; k0 += 64) {
        stage_tile(Ag, k0, Abuf, t);
        stage_tile(Bg, k0, Bbuf, t);
        __syncthreads();
        mma_step(Abuf, Bbuf, wr, wc, c, g, acc);
        __syncthreads();
    }

    ushort* E = (ushort*)(smem + (size_t)w * 8704);
    const int n0w = nblk*128 + wc*64;
    const int m0w = mblk*128 + wr*64;

    #pragma unroll
    for (int mi = 0; mi < 4; ++mi)
        #pragma unroll
        for (int ni = 0; ni < 4; ++ni) {
            float bias = bo[n0w + ni*16 + c];
            #pragma unroll
            for (int rg = 0; rg < 4; ++rg) {
                int mm = m0w + mi*16 + g*4 + rg;
                float val = acc[mi][ni][rg] + bias
                          + resid[(size_t)mm*DD + n0w + ni*16 + c];
                E[(mi*16 + g*4 + rg)*68 + ni*16 + c] = f2bf(val);
            }
        }

    const int l = lane;
    #pragma unroll
    for (int j = 0; j < 8; ++j) {
        int row = j*8 + (l >> 3);
        uint2 v0 = *(uint2*)&E[row*68 + (l & 7)*8];
        uint2 v1 = *(uint2*)&E[row*68 + (l & 7)*8 + 4];
        uint4 v = { v0.x, v0.y, v1.x, v1.y };
        *(uint4*)&out[(size_t)(m0w + row)*DD + n0w + (l & 7)*8] = v;
    }
}

// ---------------------------------------------------------------------------
// Flash attention v11: 64q PER WAVE (2 x 32q subtiles) -- every K/V LDS
// fragment read feeds TWO MFMAs, halving LDS-pipe demand per FLOP (the
// measured binding resource: ~82% LDS-busy at 32q/wave). 8 waves (4 qb x
// 2 kvh), 256q/block, grid 256 = 1 block/CU, LDS 64KB double-buffered.
// launch_bounds(512,2) -> 256 VGPR cap (peak live ~200, no spill).
// ---------------------------------------------------------------------------
__global__ __launch_bounds__(512, 2) void attn_kernel(
    const ushort* __restrict__ Q, const ushort* __restrict__ K,
    const ushort* __restrict__ Vt, ushort* __restrict__ ctx)
{
    __shared__ char smem[65536];   // K: 4 x 8KB at 0; V: 4 x 8KB at 32768

    const int t = threadIdx.x;
    const int w = t >> 6, l = t & 63;
    const int ln31 = l & 31, hi = l >> 5;
    const int qb = w & 3, kvh = w >> 2;

    const int id  = blockIdx.x;
    const int swz = (id & 7) * 32 + (id >> 3);
    const int qt2 = swz & 7;
    const int h   = (swz >> 3) & 7;
    const int b   = swz >> 6;
    const size_t bh = (size_t)b * HH + h;
    const int q0 = qt2*256 + qb*64;

    // Q fragments for both 32q subtiles (fragment-major, contiguous 512B)
    const char* Qp = (const char*)Q + (bh*64 + (size_t)(q0 >> 5)) * 4096;
    bf16x8 qf[2][4];
    #pragma unroll
    for (int qtl = 0; qtl < 2; ++qtl)
        #pragma unroll
        for (int s = 0; s < 4; ++s)
            qf[qtl][s] = *(const bf16x8*)(Qp + qtl*4096 + (2*s + hi)*512 + ln31*16);

    const int t2 = t & 255;
    const int NT = 16;
    const size_t kvbase = bh * 32;

#define KBUF(buf_) (smem + ((kvh)*2 + (buf_))*8192)
#define VBUF(buf_) (smem + 32768 + ((kvh)*2 + (buf_))*8192)

#define ATTN_STAGE(kvi, buf_) do {                                          \
        const size_t tb_ = (kvbase + (size_t)(kvh*NT + (kvi))) * 8192;      \
        const char* kp_ = (const char*)K  + tb_;                            \
        const char* vp_ = (const char*)Vt + tb_;                            \
        gload16(kp_ + t2*16,        KBUF(buf_) + t2*16);                    \
        gload16(kp_ + 4096 + t2*16, KBUF(buf_) + 4096 + t2*16);             \
        gload16(vp_ + t2*16,        VBUF(buf_) + t2*16);                    \
        gload16(vp_ + 4096 + t2*16, VBUF(buf_) + 4096 + t2*16);             \
    } while (0)

#define SOFTPACK(ST, PB, LS) do {                                           \
        _Pragma("unroll")                                                   \
        for (int kt = 0; kt < 2; ++kt)                                      \
            _Pragma("unroll")                                               \
            for (int i = 0; i < 16; ++i)                                    \
                ST[kt][i] = exp2_hw(ST[kt][i]);                             \
        {                                                                   \
            float ps_[16];                                                  \
            _Pragma("unroll")                                               \
            for (int i = 0; i < 16; ++i) ps_[i] = ST[0][i] + ST[1][i];      \
            _Pragma("unroll")                                               \
            for (int i = 0; i < 8; ++i)  ps_[i] += ps_[i+8];                \
            _Pragma("unroll")                                               \
            for (int i = 0; i < 4; ++i)  ps_[i] += ps_[i+4];                \
            float psum_ = (ps_[0] + ps_[1]) + (ps_[2] + ps_[3]);            \
            float pa_ = psum_, pb2_ = psum_;                                \
            plane_swapf(pa_, pb2_);                                         \
            LS += pa_ + pb2_;                                               \
        }                                                                   \
        unsigned dk_[2][4][2];                                              \
        _Pragma("unroll")                                                   \
        for (int kt = 0; kt < 2; ++kt)                                      \
            _Pragma("unroll")                                               \
            for (int rb = 0; rb < 4; ++rb) {                                \
                dk_[kt][rb][0] = cvt_pk_bf16(ST[kt][4*rb+0], ST[kt][4*rb+1]);\
                dk_[kt][rb][1] = cvt_pk_bf16(ST[kt][4*rb+2], ST[kt][4*rb+3]);\
            }                                                               \
        _Pragma("unroll")                                                   \
        for (int kt = 0; kt < 2; ++kt)                                      \
            _Pragma("unroll")                                               \
            for (int s2 = 0; s2 < 2; ++s2) {                                \
                unsigned a0_ = dk_[kt][2*s2][0], b0_ = dk_[kt][2*s2+1][0];  \
                unsigned a1_ = dk_[kt][2*s2][1], b1_ = dk_[kt][2*s2+1][1];  \
                plane_swap(a0_, b0_);                                       \
                plane_swap(a1_, b1_);                                       \
                PB[kt][s2] = pack4(a0_, a1_, b0_, b1_);                     \
            }                                                               \
    } while (0)

    f32x16 ot0[2] = {}, ot1[2] = {};
    float lsum0 = 0.f, lsum1 = 0.f;

    ATTN_STAGE(0, 0);

    for (int kv = 0; kv < NT; ++kv) {
        const int cur = kv & 1;
        __syncthreads();               // staged tiles ready (vmcnt drained)
        if (kv + 1 < NT) ATTN_STAGE(kv + 1, cur ^ 1);

        const char* Kc = KBUF(cur);
        const char* Vc = VBUF(cur);

        // ---- S^T = K . Q^T for BOTH q-subtiles: kf read once, used twice ----
        f32x16 st0[2] = {}, st1[2] = {};
        __builtin_amdgcn_s_setprio(1);
        #pragma unroll
        for (int kt = 0; kt < 2; ++kt)
            #pragma unroll
            for (int s = 0; s < 4; ++s) {
                bf16x8 kf = *(const bf16x8*)(Kc + ((2*s + hi) << 10)
                                                + ((kt*32 + ln31) << 4));
                st0[kt] = __builtin_amdgcn_mfma_f32_32x32x16_bf16(kf, qf[0][s], st0[kt], 0, 0, 0);
                st1[kt] = __builtin_amdgcn_mfma_f32_32x32x16_bf16(kf, qf[1][s], st1[kt], 0, 0, 0);
            }
        __builtin_amdgcn_s_setprio(0);

        // ---- softmax + pack per q-subtile ----
        bf16x8 pb0[2][2], pb1[2][2];
        SOFTPACK(st0, pb0, lsum0);
        SOFTPACK(st1, pb1, lsum1);

        // ---- O^T += V^T . P^T: vf read once, used twice ----
        __builtin_amdgcn_s_setprio(1);
        #pragma unroll
        for (int kt = 0; kt < 2; ++kt)
            #pragma unroll
            for (int s2 = 0; s2 < 2; ++s2)
                #pragma unroll
                for (int dt = 0; dt < 2; ++dt) {
                    bf16x8 vf = *(const bf16x8*)(Vc + ((kt*4 + 2*s2 + hi) << 10)
                                                   + ((dt*32 + ln31) << 4));
                    ot0[dt] = __builtin_amdgcn_mfma_f32_32x32x16_bf16(vf, pb0[kt][s2], ot0[dt], 0, 0, 0);
                    ot1[dt] = __builtin_amdgcn_mfma_f32_32x32x16_bf16(vf, pb1[kt][s2], ot1[dt], 0, 0, 0);
                }
        __builtin_amdgcn_s_setprio(0);
    }
#undef ATTN_STAGE
#undef SOFTPACK
#undef KBUF
#undef VBUF

    // ---- intra-block combine of the two kv-halves (additive partials) ----
    __syncthreads();
    float* comb = (float*)smem;            // 256 rows x 33 floats = 33792 B
    float* p0 = comb + (size_t)(qb*64 + ln31) * 33;
    float* p1 = comb + (size_t)(qb*64 + 32 + ln31) * 33;
    if (kvh == 0) {
        if (hi == 0) {
            #pragma unroll
            for (int i = 0; i < 16; ++i) { p0[i] = ot0[0][i]; p0[16+i] = ot0[1][i]; }
            p0[32] = lsum0;
            #pragma unroll
            for (int i = 0; i < 16; ++i) { p1[i] = ot1[0][i]; p1[16+i] = ot1[1][i]; }
            p1[32] = lsum1;
        }
    }
    __syncthreads();
    if (kvh == 0 && hi == 1) {
        // hi=1 lanes of kvh=0 hold rows 4..7 of each 8-row group (C/D layout:
        // row = rb*8 + hi*4 + u). Merge them into the same comb rows.
        #pragma unroll
        for (int i = 0; i < 16; ++i) { p0[i] += ot0[0][i]; p0[16+i] += ot0[1][i]; }
        #pragma unroll
        for (int i = 0; i < 16; ++i) { p1[i] += ot1[0][i]; p1[16+i] += ot1[1][i]; }
    }
    __syncthreads();
    if (kvh == 1) {
        const float rl0 = 1.f / (lsum0 + p0[32]);
        const float rl1 = 1.f / (lsum1 + p1[32]);
        ushort* outp0 = ctx + ((size_t)b*SS + q0 + ln31) * DD + h*DHH;
        ushort* outp1 = ctx + ((size_t)b*SS + q0 + 32 + ln31) * DD + h*DHH;
        #pragma unroll
        for (int dt = 0; dt < 2; ++dt)
            #pragma unroll
            for (int rb = 0; rb < 4; ++rb) {
                ushort4 o0 = { f2bf((ot0[dt][4*rb+0] + p0[dt*16+4*rb+0])*rl0),
                               f2bf((ot0[dt][4*rb+1] + p0[dt*16+4*rb+1])*rl0),
                               f2bf((ot0[dt][4*rb+2] + p0[dt*16+4*rb+2])*rl0),
                               f2bf((ot0[dt][4*rb+3] + p0[dt*16+4*rb+3])*rl0) };
                *(ushort4*)&outp0[dt*32 + rb*8 + hi*4] = o0;
                ushort4 o1 = { f2bf((ot1[dt][4*rb+0] + p1[dt*16+4*rb+0])*rl1),
                               f2bf((ot1[dt][4*rb+1] + p1[dt*16+4*rb+1])*rl1),
                               f2bf((ot1[dt][4*rb+2] + p1[dt*16+4*rb+2])*rl1),
                               f2bf((ot1[dt][4*rb+3] + p1[dt*16+4*rb+3])*rl1) };
                *(ushort4*)&outp1[dt*32 + rb*8 + hi*4] = o1;
            }
    }
}

// ---------------------------------------------------------------------------
// Row LayerNorm (bf16 input, f32 output)
// ---------------------------------------------------------------------------
__global__ __launch_bounds__(256) void ln_kernel(
    const ushort* __restrict__ y, const float* __restrict__ gamma,
    const float* __restrict__ beta, float* __restrict__ out)
{
    const int row = blockIdx.x;
    const int t = threadIdx.x;

    unsigned u = *(const unsigned*)&y[(size_t)row * DD + t*2];
    union { unsigned u; float f; } lo, hi;
    lo.u = (u & 0xFFFFu) << 16;
    hi.u = u & 0xFFFF0000u;
    float2 v = { lo.f, hi.f };

    float s  = v.x + v.y;
    float sq = v.x*v.x + v.y*v.y;
    #pragma unroll
    for (int off = 1; off < 64; off <<= 1) {
        s  += __shfl_xor(s,  off);
        sq += __shfl_xor(sq, off);
    }
    __shared__ float ss[4], ssq[4];
    int wv = t >> 6;
    if ((t & 63) == 0) { ss[wv] = s; ssq[wv] = sq; }
    __syncthreads();
    s  = ss[0] + ss[1] + ss[2] + ss[3];
    sq = ssq[0] + ssq[1] + ssq[2] + ssq[3];

    float mean = s * (1.0f / DD);
    float var  = sq * (1.0f / DD) - mean * mean;
    float rstd = rsqrtf(var + LN_EPS);

    float2 g  = *(const float2*)&gamma[t*2];
    float2 be = *(const float2*)&beta[t*2];
    float2 o;
    o.x = (v.x - mean) * rstd * g.x + be.x;
    o.y = (v.y - mean) * rstd * g.y + be.y;
    *(float2*)&out[(size_t)row * DD + t*2] = o;
}

// ---------------------------------------------------------------------------
extern "C" void kernel_launch(void* const* d_in, const int* in_sizes, int n_in,
                              void* d_out, int out_size, void* d_ws, size_t ws_size,
                              hipStream_t stream)
{
    const float* x     = (const float*)d_in[0];
    const float* wq    = (const float*)d_in[1];
    const float* bq    = (const float*)d_in[2];
    const float* wk    = (const float*)d_in[3];
    const float* bk    = (const float*)d_in[4];
    const float* wv    = (const float*)d_in[5];
    const float* bv    = (const float*)d_in[6];
    const float* wo    = (const float*)d_in[7];
    const float* bo    = (const float*)d_in[8];
    const float* gamma = (const float*)d_in[9];
    const float* beta  = (const float*)d_in[10];

    char* wsb = (char*)d_ws;
    const size_t MB = 1u << 20;
    ushort* xb    = (ushort*)(wsb + 0*MB);    // 8 MB; dead after qkv -> ybuf
    ushort* wb    = (ushort*)(wsb + 8*MB);    // 2 MB
    float*  biasc = (float* )(wsb + 10*MB);   // 6 KB
    ushort* Qb    = (ushort*)(wsb + 11*MB);   // fragment-major
    ushort* Kb    = (ushort*)(wsb + 19*MB);   // fragment-major
    ushort* Vtb   = (ushort*)(wsb + 27*MB);   // fragment-major transposed
    ushort* ctxb  = (ushort*)(wsb + 35*MB);
    ushort* ybuf  = xb;                        // alias (xb dead after qkv)

    cast_kernel<<<2048, 256, 0, stream>>>(x, wq, wk, wv, wo, bq, bk, bv,
                                          xb, wb, biasc);
    {
        qkv_mm<<<768, 256, 0, stream>>>(xb, wb, biasc, Qb, Kb, Vtb);
    }
    {
        attn_kernel<<<256, 512, 0, stream>>>(Qb, Kb, Vtb, ctxb);
    }
    {
        oproj_mm<<<256, 256, 0, stream>>>(ctxb, wb + 3*DD*DD, bo, x, ybuf);
    }
    ln_kernel<<<MROWS, 256, 0, stream>>>(ybuf, gamma, beta, (float*)d_out);
}